// Round 2
// baseline (4882.622 us; speedup 1.0000x reference)
//
#include <hip/hip_runtime.h>
#include <math.h>

// Problem constants
#define HH 128
#define WW 128
#define CC 128
#define KK 9
#define NPIX 16384           // H*W
#define NELEM 2097152        // NPIX*C
#define EPS 1e-5f

// Workspace layout (float offsets)
#define OFF_WCOMB 0          // [2][9][27][128]  = 62208
#define OFF_BCOMB 62208      // [2][32]          = 64
#define OFF_WKT   62272      // [2][9][128][128] = 294912
#define OFF_PROJT 357184     // 183808 floats (8 transposed proj matrices)
#define OFF_OFFM  540992     // [16384][27]      = 442368
#define OFF_BUFA  983360     // [16384][128]     = 2097152
#define OFF_BUFB  3080512    // [16384][128]     = 2097152
#define OFF_STATS 5177664    // [10][2][128]     = 2560
#define WS_FLOATS 5180224    // ~20.7 MB

// ---------------------------------------------------------------------------
// Setup: compose [ow;mw] @ cw -> 27-ch conv weights (layout [k][o][c]),
// composed bias, and transpose cw -> wkT [k][c][o] for the deform matvec.
// PER-BLOCK sizes: wcomb = 9*27*128 = 31104 floats, bcomb = 27, wkT = 147456.
// (Round-1 bug: wcomb branch bound was 62208 -> 2x overrun clobbered bcomb
//  and block-0 wkT. Fixed: exact per-block bounds.)
// ---------------------------------------------------------------------------
__global__ __launch_bounds__(256) void setup_conv(
    const float* __restrict__ cw, const float* __restrict__ cb,
    const float* __restrict__ ow, const float* __restrict__ mw,
    float* __restrict__ wcomb, float* __restrict__ bcomb,
    float* __restrict__ wkT)
{
    int tid = blockIdx.x * 256 + threadIdx.x;
    if (tid < 31104) {
        int c = tid & 127;
        int o = (tid >> 7) % 27;
        int k = tid / 3456;                  // k in [0,9)
        const float* sel = (o < 18) ? (ow + o * 128) : (mw + (o - 18) * 128);
        float v = 0.f;
        for (int cp = 0; cp < 128; ++cp)
            v = fmaf(sel[cp], cw[cp * 1152 + c * 9 + k], v);
        wcomb[tid] = v;                      // wcomb[k][o][c]
    } else if (tid < 31104 + 27) {
        int o = tid - 31104;
        const float* sel = (o < 18) ? (ow + o * 128) : (mw + (o - 18) * 128);
        float v = 0.f;
        for (int cp = 0; cp < 128; ++cp)
            v = fmaf(sel[cp], cb[cp], v);
        bcomb[o] = v;
    } else if (tid >= 32768 && tid < 32768 + 147456) {
        int i = tid - 32768;
        int o = i & 127;
        int c = (i >> 7) & 127;
        int k = i >> 14;
        wkT[i] = cw[o * 1152 + c * 9 + k];   // wkT[k][c][o]
    }
}

// Transpose the 8 projection matrices [O][128] -> [128][O], concatenated.
__global__ __launch_bounds__(256) void setup_proj(
    const float* __restrict__ s0, const float* __restrict__ s1,
    const float* __restrict__ s2, const float* __restrict__ s3,
    const float* __restrict__ s4, const float* __restrict__ s5,
    const float* __restrict__ s6, const float* __restrict__ s7,
    float* __restrict__ dst)
{
    const int Os[8]   = {20, 80, 150, 150, 210, 210, 308, 308};
    const int offs[8] = {0, 2560, 12800, 32000, 51200, 78080, 104960, 144384};
    int tid = blockIdx.x * 256 + threadIdx.x;
    if (tid >= 183808) return;
    int m = 0;
    #pragma unroll
    for (int j = 1; j < 8; ++j) if (tid >= offs[j]) m = j;
    const float* src;
    switch (m) {
        case 0: src = s0; break; case 1: src = s1; break;
        case 2: src = s2; break; case 3: src = s3; break;
        case 4: src = s4; break; case 5: src = s5; break;
        case 6: src = s6; break; default: src = s7; break;
    }
    int i = tid - offs[m];
    int O = Os[m];
    int c = i / O, o = i - c * O;
    dst[tid] = src[o * 128 + c];
}

// ---------------------------------------------------------------------------
// conv_offm: 27-ch 3x3 conv per pixel + softmax(mask) -> offm[py9|px9|mask9]
// 2 waves/block, 4 pixels/wave; lanes split channels (c=lane, c=lane+64).
// ---------------------------------------------------------------------------
__global__ __launch_bounds__(128, 1) void conv_offm(
    const float* __restrict__ x, const float* __restrict__ wcomb,
    const float* __restrict__ bcomb, float* __restrict__ offm)
{
    const int lane = threadIdx.x & 63;
    const int wid  = threadIdx.x >> 6;
    const int gp0  = (blockIdx.x * 2 + wid) * 4;     // 4 consecutive pixels, same row
    const int h0   = gp0 >> 7;
    const int w0   = gp0 & 127;

    float acc[4][27];
    #pragma unroll
    for (int p = 0; p < 4; ++p)
        #pragma unroll
        for (int o = 0; o < 27; ++o) acc[p][o] = 0.f;

    for (int k = 0; k < 9; ++k) {
        const int dy = k / 3 - 1, dx = k % 3 - 1;
        const int ny = h0 + dy;
        float xv0[4], xv1[4];
        #pragma unroll
        for (int p = 0; p < 4; ++p) {
            const int nx = w0 + p + dx;
            const bool ok = (ny >= 0) & (ny < HH) & (nx >= 0) & (nx < WW);
            const float* xb = x + (((ny < 0 ? 0 : (ny > 127 ? 127 : ny)) << 7)
                                   + (nx < 0 ? 0 : (nx > 127 ? 127 : nx))) * 128;
            xv0[p] = ok ? xb[lane]      : 0.f;
            xv1[p] = ok ? xb[lane + 64] : 0.f;
        }
        const float* wb = wcomb + k * 27 * 128;
        #pragma unroll
        for (int o = 0; o < 27; ++o) {
            const float wv0 = wb[o * 128 + lane];
            const float wv1 = wb[o * 128 + 64 + lane];
            #pragma unroll
            for (int p = 0; p < 4; ++p)
                acc[p][o] = fmaf(xv0[p], wv0, fmaf(xv1[p], wv1, acc[p][o]));
        }
    }

    // cross-lane butterfly reduce each of the 108 partials
    #pragma unroll
    for (int p = 0; p < 4; ++p)
        #pragma unroll
        for (int o = 0; o < 27; ++o) {
            float v = acc[p][o];
            v += __shfl_xor(v, 32);
            v += __shfl_xor(v, 16);
            v += __shfl_xor(v, 8);
            v += __shfl_xor(v, 4);
            v += __shfl_xor(v, 2);
            v += __shfl_xor(v, 1);
            acc[p][o] = v;
        }

    #pragma unroll
    for (int p = 0; p < 4; ++p) {
        if (lane == p) {
            const int gp = gp0 + p;
            const int hh = gp >> 7, ww = gp & 127;
            float vals[27];
            #pragma unroll
            for (int o = 0; o < 27; ++o) vals[o] = acc[p][o] + bcomb[o];
            float mx = vals[18];
            #pragma unroll
            for (int k = 1; k < 9; ++k) mx = fmaxf(mx, vals[18 + k]);
            float e[9], se = 0.f;
            #pragma unroll
            for (int k = 0; k < 9; ++k) { e[k] = expf(vals[18 + k] - mx); se += e[k]; }
            const float inv = 1.f / se;
            float* ob = offm + gp * 27;
            #pragma unroll
            for (int k = 0; k < 9; ++k) {
                ob[k]      = (float)(hh - 1 + k / 3) + vals[2 * k];      // py
                ob[9 + k]  = (float)(ww - 1 + k % 3) + vals[2 * k + 1];  // px
                ob[18 + k] = e[k] * inv;                                 // mask
            }
        }
    }
}

// ---------------------------------------------------------------------------
// deform: bilinear gather (samp -> LDS, pixel-minor pack) + 128x1152 matvec.
// 2 waves/block, 8 pixels/block, split-K across the two waves.
// ---------------------------------------------------------------------------
__global__ __launch_bounds__(128, 1) void deform_kernel(
    const float* __restrict__ x, const float* __restrict__ offm,
    const float* __restrict__ wkT, const float* __restrict__ cb,
    float* __restrict__ y)
{
    __shared__ float4 smA4[1152];   // pixels 0..3, [kc][4]
    __shared__ float4 smB4[1152];   // pixels 4..7
    __shared__ float  part[1024];
    float* smA = (float*)smA4;
    float* smB = (float*)smB4;

    const int lane = threadIdx.x & 63;
    const int wid  = threadIdx.x >> 6;
    const int gp0  = blockIdx.x * 8;

    // ---- phase 1: wave wid gathers pixels [4*wid, 4*wid+4) ----
    float* smw = wid ? smB : smA;
    for (int pp = 0; pp < 4; ++pp) {
        const int gp = gp0 + 4 * wid + pp;
        const float* ob = offm + gp * 27;
        for (int k = 0; k < 9; ++k) {
            const float py = ob[k], px = ob[9 + k], mk = ob[18 + k];
            const float y0f = floorf(py), x0f = floorf(px);
            const int iy0 = (int)y0f, ix0 = (int)x0f;
            const float wy1 = py - y0f, wy0 = 1.f - wy1;
            const float wx1 = px - x0f, wx0 = 1.f - wx1;
            float s0 = 0.f, s1 = 0.f;
            #pragma unroll
            for (int cy = 0; cy < 2; ++cy) {
                const int yy = iy0 + cy;
                if (yy < 0 || yy > 127) continue;
                const float wy = cy ? wy1 : wy0;
                #pragma unroll
                for (int cx = 0; cx < 2; ++cx) {
                    const int xx = ix0 + cx;
                    if (xx < 0 || xx > 127) continue;
                    const float wgt = wy * (cx ? wx1 : wx0);
                    const float* xb = x + (((yy << 7) + xx) << 7);
                    s0 = fmaf(wgt, xb[lane], s0);
                    s1 = fmaf(wgt, xb[lane + 64], s1);
                }
            }
            smw[(k * 128 + lane) * 4 + pp]      = s0 * mk;
            smw[(k * 128 + 64 + lane) * 4 + pp] = s1 * mk;
        }
    }
    __syncthreads();

    // ---- phase 2: wave wid handles kc in [wid*576, wid*576+576) ----
    float acc0[8], acc1[8];
    #pragma unroll
    for (int p = 0; p < 8; ++p) { acc0[p] = 0.f; acc1[p] = 0.f; }
    const int kc0 = wid * 576;
    const float* wp = wkT + kc0 * 128;
    #pragma unroll 2
    for (int i = 0; i < 576; ++i) {
        const float w0 = wp[i * 128 + lane];
        const float w1 = wp[i * 128 + 64 + lane];
        const float4 a = smA4[kc0 + i];
        const float4 b = smB4[kc0 + i];
        acc0[0] = fmaf(a.x, w0, acc0[0]); acc0[1] = fmaf(a.y, w0, acc0[1]);
        acc0[2] = fmaf(a.z, w0, acc0[2]); acc0[3] = fmaf(a.w, w0, acc0[3]);
        acc0[4] = fmaf(b.x, w0, acc0[4]); acc0[5] = fmaf(b.y, w0, acc0[5]);
        acc0[6] = fmaf(b.z, w0, acc0[6]); acc0[7] = fmaf(b.w, w0, acc0[7]);
        acc1[0] = fmaf(a.x, w1, acc1[0]); acc1[1] = fmaf(a.y, w1, acc1[1]);
        acc1[2] = fmaf(a.z, w1, acc1[2]); acc1[3] = fmaf(a.w, w1, acc1[3]);
        acc1[4] = fmaf(b.x, w1, acc1[4]); acc1[5] = fmaf(b.y, w1, acc1[5]);
        acc1[6] = fmaf(b.z, w1, acc1[6]); acc1[7] = fmaf(b.w, w1, acc1[7]);
    }

    if (wid == 1) {
        #pragma unroll
        for (int p = 0; p < 8; ++p) {
            part[p * 64 + lane]       = acc0[p];
            part[512 + p * 64 + lane] = acc1[p];
        }
    }
    __syncthreads();
    if (wid == 0) {
        const float b0 = cb[lane], b1 = cb[lane + 64];
        #pragma unroll
        for (int p = 0; p < 8; ++p) {
            const float v0 = acc0[p] + part[p * 64 + lane] + b0;
            const float v1 = acc1[p] + part[512 + p * 64 + lane] + b1;
            y[(gp0 + p) * 128 + lane]      = v0;
            y[(gp0 + p) * 128 + 64 + lane] = v1;
        }
    }
}

// ---------------------------------------------------------------------------
// Per-channel sum / sumsq over the image (for the BN-style normalization).
// ---------------------------------------------------------------------------
__global__ __launch_bounds__(256) void stats_kernel(
    const float* __restrict__ y, float* __restrict__ stats)
{
    const int g = blockIdx.x * 256 + threadIdx.x;   // grid 256 -> 65536 threads
    float s = 0.f, q = 0.f;
    for (int i = g; i < NELEM; i += 65536) {
        const float v = y[i];
        s += v;
        q = fmaf(v, v, q);
    }
    __shared__ float ls[256], lq[256];
    ls[threadIdx.x] = s; lq[threadIdx.x] = q;
    __syncthreads();
    if (threadIdx.x < 128) {
        atomicAdd(&stats[threadIdx.x],       ls[threadIdx.x] + ls[threadIdx.x + 128]);
        atomicAdd(&stats[128 + threadIdx.x], lq[threadIdx.x] + lq[threadIdx.x + 128]);
    }
}

__global__ __launch_bounds__(256) void norm_relu(
    float* __restrict__ y, const float* __restrict__ stats,
    const float* __restrict__ bg, const float* __restrict__ bb)
{
    const int g = blockIdx.x * 256 + threadIdx.x;
    const int c = g & 127;
    const float mean = stats[c] * (1.f / 16384.f);
    const float var  = stats[128 + c] * (1.f / 16384.f) - mean * mean;
    const float rstd = rsqrtf(var + EPS);
    const float scale = bg[c] * rstd;
    const float shift = bb[c] - mean * scale;
    for (int i = g; i < NELEM; i += 65536)
        y[i] = fmaxf(fmaf(y[i], scale, shift), 0.f);
}

// ---------------------------------------------------------------------------
// 1x1 projection: 64-pixel LDS tile (stride 129 -> conflict free), lanes over
// pixels for coalesced NCHW writes; weight loads are wave-uniform.
// ---------------------------------------------------------------------------
__global__ __launch_bounds__(256) void proj_kernel(
    const float* __restrict__ xin, const float* __restrict__ wT,
    float* __restrict__ out, int O, int accum)
{
    __shared__ float tile[64 * 129];
    const int gp0 = blockIdx.x * 64;
    for (int i = threadIdx.x; i < 8192; i += 256) {
        const int p = i >> 7, c = i & 127;
        tile[p * 129 + c] = xin[(gp0 + p) * 128 + c];
    }
    __syncthreads();
    const int p  = threadIdx.x & 63;
    const int wv = threadIdx.x >> 6;
    const float* row = tile + p * 129;
    for (int o = wv; o < O; o += 4) {
        float acc = 0.f;
        #pragma unroll 4
        for (int c = 0; c < 128; ++c)
            acc = fmaf(row[c], wT[c * O + o], acc);
        float* dst = out + o * NPIX + gp0 + p;
        *dst = accum ? (*dst + acc) : acc;
    }
}

// ---------------------------------------------------------------------------
// Final layernorm over the W axis: one wave per (c,h) row of 128.
// ---------------------------------------------------------------------------
__global__ __launch_bounds__(256) void final_ln(
    float* __restrict__ out, const float* __restrict__ lnw,
    const float* __restrict__ lnb)
{
    const int lane = threadIdx.x & 63;
    const int wid  = threadIdx.x >> 6;
    const int row  = blockIdx.x * 4 + wid;          // 98304 rows
    float* rp = out + row * 128;
    const float v0 = rp[lane], v1 = rp[lane + 64];
    float s = v0 + v1;
    float q = v0 * v0 + v1 * v1;
    #pragma unroll
    for (int m = 32; m; m >>= 1) {
        s += __shfl_xor(s, m);
        q += __shfl_xor(q, m);
    }
    const float mean = s * (1.f / 128.f);
    const float var  = q * (1.f / 128.f) - mean * mean;
    const float rstd = rsqrtf(var + EPS);
    rp[lane]      = (v0 - mean) * rstd * lnw[lane]      + lnb[lane];
    rp[lane + 64] = (v1 - mean) * rstd * lnw[lane + 64] + lnb[lane + 64];
}

// ---------------------------------------------------------------------------
extern "C" void kernel_launch(void* const* d_in, const int* in_sizes, int n_in,
                              void* d_out, int out_size, void* d_ws, size_t ws_size,
                              hipStream_t stream)
{
    const float* xin[5];
    for (int i = 0; i < 5; ++i) xin[i] = (const float*)d_in[i];
    const float* b_cw[2] = {(const float*)d_in[5],  (const float*)d_in[11]};
    const float* b_cb[2] = {(const float*)d_in[6],  (const float*)d_in[12]};
    const float* b_ow[2] = {(const float*)d_in[7],  (const float*)d_in[13]};
    const float* b_mw[2] = {(const float*)d_in[8],  (const float*)d_in[14]};
    const float* b_bg[2] = {(const float*)d_in[9],  (const float*)d_in[15]};
    const float* b_bb[2] = {(const float*)d_in[10], (const float*)d_in[16]};
    const float* pw[8];
    for (int i = 0; i < 8; ++i) pw[i] = (const float*)d_in[17 + i];
    const float* lnw = (const float*)d_in[25];
    const float* lnb = (const float*)d_in[26];

    float* W = (float*)d_ws;
    float* out = (float*)d_out;

    hipMemsetAsync(W + OFF_STATS, 0, 2560 * sizeof(float), stream);

    setup_conv<<<704, 256, 0, stream>>>(b_cw[0], b_cb[0], b_ow[0], b_mw[0],
        W + OFF_WCOMB, W + OFF_BCOMB, W + OFF_WKT);
    setup_conv<<<704, 256, 0, stream>>>(b_cw[1], b_cb[1], b_ow[1], b_mw[1],
        W + OFF_WCOMB + 31104, W + OFF_BCOMB + 32, W + OFF_WKT + 147456);
    setup_proj<<<718, 256, 0, stream>>>(pw[0], pw[1], pw[2], pw[3],
        pw[4], pw[5], pw[6], pw[7], W + OFF_PROJT);

    static const int Obase[5] = {0, 20, 100, 250, 460};
    static const int Ocnt[5]  = {20, 80, 150, 210, 308};
    static const int taOff[5] = {0, 2560, 12800, 51200, 104960};
    static const int tbOff[5] = {0, 0, 32000, 78080, 144384};

    for (int img = 0; img < 5; ++img) {
        for (int blk = 0; blk < 2; ++blk) {
            const float* xb = (blk == 0) ? xin[img] : (W + OFF_BUFA);
            float* yb = (blk == 0) ? (W + OFF_BUFA) : (W + OFF_BUFB);
            conv_offm<<<2048, 128, 0, stream>>>(
                xb, W + OFF_WCOMB + blk * 31104, W + OFF_BCOMB + blk * 32,
                W + OFF_OFFM);
            deform_kernel<<<2048, 128, 0, stream>>>(
                xb, W + OFF_OFFM, W + OFF_WKT + blk * 147456, b_cb[blk], yb);
            float* st = W + OFF_STATS + (img * 2 + blk) * 256;
            stats_kernel<<<256, 256, 0, stream>>>(yb, st);
            norm_relu<<<256, 256, 0, stream>>>(yb, st, b_bg[blk], b_bb[blk]);
        }
        float* outb = out + (size_t)Obase[img] * NPIX;
        proj_kernel<<<256, 256, 0, stream>>>(
            W + OFF_BUFB, W + OFF_PROJT + taOff[img], outb, Ocnt[img], 0);
        if (img >= 2)
            proj_kernel<<<256, 256, 0, stream>>>(
                xin[img], W + OFF_PROJT + tbOff[img], outb, Ocnt[img], 1);
    }
    final_ln<<<24576, 256, 0, stream>>>(out, lnw, lnb);
}

// Round 3
// 3468.677 us; speedup vs baseline: 1.4076x; 1.4076x over previous
//
#include <hip/hip_runtime.h>
#include <math.h>

// Problem constants
#define HH 128
#define WW 128
#define CC 128
#define KK 9
#define NPIX 16384           // H*W
#define NELEM 2097152        // NPIX*C
#define EPS 1e-5f

// Workspace layout (float offsets)
#define OFF_WCOMB 0          // [2][9][27][128]  = 62208
#define OFF_BCOMB 62208      // [2][32]          = 64
#define OFF_WKT   62272      // [2][9][128][128] = 294912
#define OFF_PROJT 357184     // 187392 floats (8 transposed+padded proj mats)
#define OFF_OFFM  544576     // [16384][27]      = 442368
#define OFF_BUFA  986944     // [16384][128]     = 2097152
#define OFF_BUFB  3084096    // [16384][128]     = 2097152
#define OFF_STATS 5181248    // [10][2][128]     = 2560
#define WS_FLOATS 5183808    // ~20.7 MB

// ---------------------------------------------------------------------------
// Setup: compose [ow;mw] @ cw -> 27-ch conv weights (layout [k][o][c]),
// composed bias, and transpose cw -> wkT [k][c][o] for the deform matvec.
// PER-BLOCK sizes: wcomb = 9*27*128 = 31104 floats, bcomb = 27, wkT = 147456.
// ---------------------------------------------------------------------------
__global__ __launch_bounds__(256) void setup_conv(
    const float* __restrict__ cw, const float* __restrict__ cb,
    const float* __restrict__ ow, const float* __restrict__ mw,
    float* __restrict__ wcomb, float* __restrict__ bcomb,
    float* __restrict__ wkT)
{
    int tid = blockIdx.x * 256 + threadIdx.x;
    if (tid < 31104) {
        int c = tid & 127;
        int o = (tid >> 7) % 27;
        int k = tid / 3456;                  // k in [0,9)
        const float* sel = (o < 18) ? (ow + o * 128) : (mw + (o - 18) * 128);
        float v = 0.f;
        for (int cp = 0; cp < 128; ++cp)
            v = fmaf(sel[cp], cw[cp * 1152 + c * 9 + k], v);
        wcomb[tid] = v;                      // wcomb[k][o][c]
    } else if (tid < 31104 + 27) {
        int o = tid - 31104;
        const float* sel = (o < 18) ? (ow + o * 128) : (mw + (o - 18) * 128);
        float v = 0.f;
        for (int cp = 0; cp < 128; ++cp)
            v = fmaf(sel[cp], cb[cp], v);
        bcomb[o] = v;
    } else if (tid >= 32768 && tid < 32768 + 147456) {
        int i = tid - 32768;
        int o = i & 127;
        int c = (i >> 7) & 127;
        int k = i >> 14;
        wkT[i] = cw[o * 1152 + c * 9 + k];   // wkT[k][c][o]
    }
}

// Transpose the 8 projection matrices [O][128] -> padded [128][Opad],
// Opad = 8*ceil(O/8); pad entries zeroed so float4 weight loads are safe.
__global__ __launch_bounds__(256) void setup_proj(
    const float* __restrict__ s0, const float* __restrict__ s1,
    const float* __restrict__ s2, const float* __restrict__ s3,
    const float* __restrict__ s4, const float* __restrict__ s5,
    const float* __restrict__ s6, const float* __restrict__ s7,
    float* __restrict__ dst)
{
    const int Os[8]   = {20, 80, 150, 150, 210, 210, 308, 308};
    const int Op[8]   = {24, 80, 152, 152, 216, 216, 312, 312};
    const int offs[8] = {0, 3072, 13312, 32768, 52224, 79872, 107520, 147456};
    int tid = blockIdx.x * 256 + threadIdx.x;
    if (tid >= 187392) return;
    int m = 0;
    #pragma unroll
    for (int j = 1; j < 8; ++j) if (tid >= offs[j]) m = j;
    const float* src;
    switch (m) {
        case 0: src = s0; break; case 1: src = s1; break;
        case 2: src = s2; break; case 3: src = s3; break;
        case 4: src = s4; break; case 5: src = s5; break;
        case 6: src = s6; break; default: src = s7; break;
    }
    int i = tid - offs[m];
    int O = Os[m], Opad = Op[m];
    int c = i / Opad, o = i - c * Opad;
    dst[tid] = (o < O) ? src[o * 128 + c] : 0.f;
}

// ---------------------------------------------------------------------------
// conv_offm: 27-ch 3x3 conv per pixel + softmax(mask) -> offm[py9|px9|mask9]
// 2 waves/block, 4 pixels/wave; lanes split channels (c=lane, c=lane+64).
// ---------------------------------------------------------------------------
__global__ __launch_bounds__(128, 1) void conv_offm(
    const float* __restrict__ x, const float* __restrict__ wcomb,
    const float* __restrict__ bcomb, float* __restrict__ offm)
{
    const int lane = threadIdx.x & 63;
    const int wid  = threadIdx.x >> 6;
    const int gp0  = (blockIdx.x * 2 + wid) * 4;     // 4 consecutive pixels, same row
    const int h0   = gp0 >> 7;
    const int w0   = gp0 & 127;

    float acc[4][27];
    #pragma unroll
    for (int p = 0; p < 4; ++p)
        #pragma unroll
        for (int o = 0; o < 27; ++o) acc[p][o] = 0.f;

    for (int k = 0; k < 9; ++k) {
        const int dy = k / 3 - 1, dx = k % 3 - 1;
        const int ny = h0 + dy;
        float xv0[4], xv1[4];
        #pragma unroll
        for (int p = 0; p < 4; ++p) {
            const int nx = w0 + p + dx;
            const bool ok = (ny >= 0) & (ny < HH) & (nx >= 0) & (nx < WW);
            const float* xb = x + (((ny < 0 ? 0 : (ny > 127 ? 127 : ny)) << 7)
                                   + (nx < 0 ? 0 : (nx > 127 ? 127 : nx))) * 128;
            xv0[p] = ok ? xb[lane]      : 0.f;
            xv1[p] = ok ? xb[lane + 64] : 0.f;
        }
        const float* wb = wcomb + k * 27 * 128;
        #pragma unroll
        for (int o = 0; o < 27; ++o) {
            const float wv0 = wb[o * 128 + lane];
            const float wv1 = wb[o * 128 + 64 + lane];
            #pragma unroll
            for (int p = 0; p < 4; ++p)
                acc[p][o] = fmaf(xv0[p], wv0, fmaf(xv1[p], wv1, acc[p][o]));
        }
    }

    // cross-lane butterfly reduce each of the 108 partials
    #pragma unroll
    for (int p = 0; p < 4; ++p)
        #pragma unroll
        for (int o = 0; o < 27; ++o) {
            float v = acc[p][o];
            v += __shfl_xor(v, 32);
            v += __shfl_xor(v, 16);
            v += __shfl_xor(v, 8);
            v += __shfl_xor(v, 4);
            v += __shfl_xor(v, 2);
            v += __shfl_xor(v, 1);
            acc[p][o] = v;
        }

    #pragma unroll
    for (int p = 0; p < 4; ++p) {
        if (lane == p) {
            const int gp = gp0 + p;
            const int hh = gp >> 7, ww = gp & 127;
            float vals[27];
            #pragma unroll
            for (int o = 0; o < 27; ++o) vals[o] = acc[p][o] + bcomb[o];
            float mx = vals[18];
            #pragma unroll
            for (int k = 1; k < 9; ++k) mx = fmaxf(mx, vals[18 + k]);
            float e[9], se = 0.f;
            #pragma unroll
            for (int k = 0; k < 9; ++k) { e[k] = expf(vals[18 + k] - mx); se += e[k]; }
            const float inv = 1.f / se;
            float* ob = offm + gp * 27;
            #pragma unroll
            for (int k = 0; k < 9; ++k) {
                ob[k]      = (float)(hh - 1 + k / 3) + vals[2 * k];      // py
                ob[9 + k]  = (float)(ww - 1 + k % 3) + vals[2 * k + 1];  // px
                ob[18 + k] = e[k] * inv;                                 // mask
            }
        }
    }
}

// ---------------------------------------------------------------------------
// deform: bilinear gather (samp -> LDS, pixel-minor pack) + 128x1152 matvec.
// 2 waves/block, 8 pixels/block, split-K across the two waves.
// ---------------------------------------------------------------------------
__global__ __launch_bounds__(128, 1) void deform_kernel(
    const float* __restrict__ x, const float* __restrict__ offm,
    const float* __restrict__ wkT, const float* __restrict__ cb,
    float* __restrict__ y)
{
    __shared__ float4 smA4[1152];   // pixels 0..3, [kc][4]
    __shared__ float4 smB4[1152];   // pixels 4..7
    __shared__ float  part[1024];
    float* smA = (float*)smA4;
    float* smB = (float*)smB4;

    const int lane = threadIdx.x & 63;
    const int wid  = threadIdx.x >> 6;
    const int gp0  = blockIdx.x * 8;

    // ---- phase 1: wave wid gathers pixels [4*wid, 4*wid+4) ----
    float* smw = wid ? smB : smA;
    for (int pp = 0; pp < 4; ++pp) {
        const int gp = gp0 + 4 * wid + pp;
        const float* ob = offm + gp * 27;
        for (int k = 0; k < 9; ++k) {
            const float py = ob[k], px = ob[9 + k], mk = ob[18 + k];
            const float y0f = floorf(py), x0f = floorf(px);
            const int iy0 = (int)y0f, ix0 = (int)x0f;
            const float wy1 = py - y0f, wy0 = 1.f - wy1;
            const float wx1 = px - x0f, wx0 = 1.f - wx1;
            float s0 = 0.f, s1 = 0.f;
            #pragma unroll
            for (int cy = 0; cy < 2; ++cy) {
                const int yy = iy0 + cy;
                if (yy < 0 || yy > 127) continue;
                const float wy = cy ? wy1 : wy0;
                #pragma unroll
                for (int cx = 0; cx < 2; ++cx) {
                    const int xx = ix0 + cx;
                    if (xx < 0 || xx > 127) continue;
                    const float wgt = wy * (cx ? wx1 : wx0);
                    const float* xb = x + (((yy << 7) + xx) << 7);
                    s0 = fmaf(wgt, xb[lane], s0);
                    s1 = fmaf(wgt, xb[lane + 64], s1);
                }
            }
            smw[(k * 128 + lane) * 4 + pp]      = s0 * mk;
            smw[(k * 128 + 64 + lane) * 4 + pp] = s1 * mk;
        }
    }
    __syncthreads();

    // ---- phase 2: wave wid handles kc in [wid*576, wid*576+576) ----
    float acc0[8], acc1[8];
    #pragma unroll
    for (int p = 0; p < 8; ++p) { acc0[p] = 0.f; acc1[p] = 0.f; }
    const int kc0 = wid * 576;
    const float* wp = wkT + kc0 * 128;
    #pragma unroll 2
    for (int i = 0; i < 576; ++i) {
        const float w0 = wp[i * 128 + lane];
        const float w1 = wp[i * 128 + 64 + lane];
        const float4 a = smA4[kc0 + i];
        const float4 b = smB4[kc0 + i];
        acc0[0] = fmaf(a.x, w0, acc0[0]); acc0[1] = fmaf(a.y, w0, acc0[1]);
        acc0[2] = fmaf(a.z, w0, acc0[2]); acc0[3] = fmaf(a.w, w0, acc0[3]);
        acc0[4] = fmaf(b.x, w0, acc0[4]); acc0[5] = fmaf(b.y, w0, acc0[5]);
        acc0[6] = fmaf(b.z, w0, acc0[6]); acc0[7] = fmaf(b.w, w0, acc0[7]);
        acc1[0] = fmaf(a.x, w1, acc1[0]); acc1[1] = fmaf(a.y, w1, acc1[1]);
        acc1[2] = fmaf(a.z, w1, acc1[2]); acc1[3] = fmaf(a.w, w1, acc1[3]);
        acc1[4] = fmaf(b.x, w1, acc1[4]); acc1[5] = fmaf(b.y, w1, acc1[5]);
        acc1[6] = fmaf(b.z, w1, acc1[6]); acc1[7] = fmaf(b.w, w1, acc1[7]);
    }

    if (wid == 1) {
        #pragma unroll
        for (int p = 0; p < 8; ++p) {
            part[p * 64 + lane]       = acc0[p];
            part[512 + p * 64 + lane] = acc1[p];
        }
    }
    __syncthreads();
    if (wid == 0) {
        const float b0 = cb[lane], b1 = cb[lane + 64];
        #pragma unroll
        for (int p = 0; p < 8; ++p) {
            const float v0 = acc0[p] + part[p * 64 + lane] + b0;
            const float v1 = acc1[p] + part[512 + p * 64 + lane] + b1;
            y[(gp0 + p) * 128 + lane]      = v0;
            y[(gp0 + p) * 128 + 64 + lane] = v1;
        }
    }
}

// ---------------------------------------------------------------------------
// Per-channel sum / sumsq over the image (for the BN-style normalization).
// ---------------------------------------------------------------------------
__global__ __launch_bounds__(256) void stats_kernel(
    const float* __restrict__ y, float* __restrict__ stats)
{
    const int g = blockIdx.x * 256 + threadIdx.x;   // grid 256 -> 65536 threads
    float s = 0.f, q = 0.f;
    for (int i = g; i < NELEM; i += 65536) {
        const float v = y[i];
        s += v;
        q = fmaf(v, v, q);
    }
    __shared__ float ls[256], lq[256];
    ls[threadIdx.x] = s; lq[threadIdx.x] = q;
    __syncthreads();
    if (threadIdx.x < 128) {
        atomicAdd(&stats[threadIdx.x],       ls[threadIdx.x] + ls[threadIdx.x + 128]);
        atomicAdd(&stats[128 + threadIdx.x], lq[threadIdx.x] + lq[threadIdx.x + 128]);
    }
}

__global__ __launch_bounds__(256) void norm_relu(
    float* __restrict__ y, const float* __restrict__ stats,
    const float* __restrict__ bg, const float* __restrict__ bb)
{
    const int g = blockIdx.x * 256 + threadIdx.x;
    const int c = g & 127;
    const float mean = stats[c] * (1.f / 16384.f);
    const float var  = stats[128 + c] * (1.f / 16384.f) - mean * mean;
    const float rstd = rsqrtf(var + EPS);
    const float scale = bg[c] * rstd;
    const float shift = bb[c] - mean * scale;
    for (int i = g; i < NELEM; i += 65536)
        y[i] = fmaxf(fmaf(y[i], scale, shift), 0.f);
}

// ---------------------------------------------------------------------------
// 1x1 projection, register-blocked tile GEMM.
// Grid (256 pixel-tiles, ceil(O/32)); 4 waves/block; each wave computes 8
// consecutive outputs over a 64-pixel LDS tile (stride 129, conflict-free).
// Weights are padded [c][Opad] so per-c fetch = two broadcast float4 loads.
// ---------------------------------------------------------------------------
__global__ __launch_bounds__(256) void proj_kernel(
    const float* __restrict__ xin, const float* __restrict__ wT,
    float* __restrict__ out, int O, int Opad, int accum)
{
    __shared__ float tile[64 * 129];
    const int gp0 = blockIdx.x * 64;
    for (int i = threadIdx.x; i < 8192; i += 256) {
        const int p = i >> 7, c = i & 127;
        tile[p * 129 + c] = xin[(gp0 + p) * 128 + c];
    }
    __syncthreads();

    const int p  = threadIdx.x & 63;
    const int wv = threadIdx.x >> 6;
    const int ob = blockIdx.y * 32 + wv * 8;
    if (ob >= O) return;

    const float* row = tile + p * 129;
    const float* wp  = wT + ob;
    float acc[8] = {0.f, 0.f, 0.f, 0.f, 0.f, 0.f, 0.f, 0.f};
    #pragma unroll 4
    for (int c = 0; c < 128; ++c) {
        const float  v  = row[c];
        const float4 w0 = *(const float4*)(wp + c * Opad);
        const float4 w1 = *(const float4*)(wp + c * Opad + 4);
        acc[0] = fmaf(v, w0.x, acc[0]); acc[1] = fmaf(v, w0.y, acc[1]);
        acc[2] = fmaf(v, w0.z, acc[2]); acc[3] = fmaf(v, w0.w, acc[3]);
        acc[4] = fmaf(v, w1.x, acc[4]); acc[5] = fmaf(v, w1.y, acc[5]);
        acc[6] = fmaf(v, w1.z, acc[6]); acc[7] = fmaf(v, w1.w, acc[7]);
    }
    #pragma unroll
    for (int j = 0; j < 8; ++j) {
        if (ob + j < O) {
            float* dst = out + (size_t)(ob + j) * NPIX + gp0 + p;
            *dst = accum ? (*dst + acc[j]) : acc[j];
        }
    }
}

// ---------------------------------------------------------------------------
// Final layernorm over the W axis: one wave per (c,h) row of 128.
// ---------------------------------------------------------------------------
__global__ __launch_bounds__(256) void final_ln(
    float* __restrict__ out, const float* __restrict__ lnw,
    const float* __restrict__ lnb)
{
    const int lane = threadIdx.x & 63;
    const int wid  = threadIdx.x >> 6;
    const int row  = blockIdx.x * 4 + wid;          // 98304 rows
    float* rp = out + row * 128;
    const float v0 = rp[lane], v1 = rp[lane + 64];
    float s = v0 + v1;
    float q = v0 * v0 + v1 * v1;
    #pragma unroll
    for (int m = 32; m; m >>= 1) {
        s += __shfl_xor(s, m);
        q += __shfl_xor(q, m);
    }
    const float mean = s * (1.f / 128.f);
    const float var  = q * (1.f / 128.f) - mean * mean;
    const float rstd = rsqrtf(var + EPS);
    rp[lane]      = (v0 - mean) * rstd * lnw[lane]      + lnb[lane];
    rp[lane + 64] = (v1 - mean) * rstd * lnw[lane + 64] + lnb[lane + 64];
}

// ---------------------------------------------------------------------------
extern "C" void kernel_launch(void* const* d_in, const int* in_sizes, int n_in,
                              void* d_out, int out_size, void* d_ws, size_t ws_size,
                              hipStream_t stream)
{
    const float* xin[5];
    for (int i = 0; i < 5; ++i) xin[i] = (const float*)d_in[i];
    const float* b_cw[2] = {(const float*)d_in[5],  (const float*)d_in[11]};
    const float* b_cb[2] = {(const float*)d_in[6],  (const float*)d_in[12]};
    const float* b_ow[2] = {(const float*)d_in[7],  (const float*)d_in[13]};
    const float* b_mw[2] = {(const float*)d_in[8],  (const float*)d_in[14]};
    const float* b_bg[2] = {(const float*)d_in[9],  (const float*)d_in[15]};
    const float* b_bb[2] = {(const float*)d_in[10], (const float*)d_in[16]};
    const float* pw[8];
    for (int i = 0; i < 8; ++i) pw[i] = (const float*)d_in[17 + i];
    const float* lnw = (const float*)d_in[25];
    const float* lnb = (const float*)d_in[26];

    float* W = (float*)d_ws;
    float* out = (float*)d_out;

    hipMemsetAsync(W + OFF_STATS, 0, 2560 * sizeof(float), stream);

    setup_conv<<<704, 256, 0, stream>>>(b_cw[0], b_cb[0], b_ow[0], b_mw[0],
        W + OFF_WCOMB, W + OFF_BCOMB, W + OFF_WKT);
    setup_conv<<<704, 256, 0, stream>>>(b_cw[1], b_cb[1], b_ow[1], b_mw[1],
        W + OFF_WCOMB + 31104, W + OFF_BCOMB + 32, W + OFF_WKT + 147456);
    setup_proj<<<732, 256, 0, stream>>>(pw[0], pw[1], pw[2], pw[3],
        pw[4], pw[5], pw[6], pw[7], W + OFF_PROJT);

    static const int Obase[5]  = {0, 20, 100, 250, 460};
    static const int Ocnt[5]   = {20, 80, 150, 210, 308};
    static const int Opad5[5]  = {24, 80, 152, 216, 312};
    static const int taOff[5]  = {0, 3072, 13312, 52224, 107520};   // c1w,c2w,c3aw,c4aw,c5aw
    static const int tbOff[5]  = {0, 0, 32768, 79872, 147456};      // c3bw,c4bw,c5bw

    for (int img = 0; img < 5; ++img) {
        for (int blk = 0; blk < 2; ++blk) {
            const float* xb = (blk == 0) ? xin[img] : (W + OFF_BUFA);
            float* yb = (blk == 0) ? (W + OFF_BUFA) : (W + OFF_BUFB);
            conv_offm<<<2048, 128, 0, stream>>>(
                xb, W + OFF_WCOMB + blk * 31104, W + OFF_BCOMB + blk * 32,
                W + OFF_OFFM);
            deform_kernel<<<2048, 128, 0, stream>>>(
                xb, W + OFF_OFFM, W + OFF_WKT + blk * 147456, b_cb[blk], yb);
            float* st = W + OFF_STATS + (img * 2 + blk) * 256;
            stats_kernel<<<256, 256, 0, stream>>>(yb, st);
            norm_relu<<<256, 256, 0, stream>>>(yb, st, b_bg[blk], b_bb[blk]);
        }
        float* outb = out + (size_t)Obase[img] * NPIX;
        const int oTiles = (Ocnt[img] + 31) / 32;
        proj_kernel<<<dim3(256, oTiles), 256, 0, stream>>>(
            W + OFF_BUFB, W + OFF_PROJT + taOff[img], outb,
            Ocnt[img], Opad5[img], 0);
        if (img >= 2)
            proj_kernel<<<dim3(256, oTiles), 256, 0, stream>>>(
                xin[img], W + OFF_PROJT + tbOff[img], outb,
                Ocnt[img], Opad5[img], 1);
    }
    final_ln<<<24576, 256, 0, stream>>>(out, lnw, lnb);
}

// Round 4
// 2287.632 us; speedup vs baseline: 2.1344x; 1.5163x over previous
//
#include <hip/hip_runtime.h>
#include <math.h>

// Problem constants
#define HH 128
#define WW 128
#define CC 128
#define KK 9
#define NPIX 16384           // H*W
#define NELEM 2097152        // NPIX*C
#define EPS 1e-5f

// Workspace layout (float offsets)
#define OFF_WCOMB 0          // [2][9][27][128]  = 62208
#define OFF_BCOMB 62208      // [2][32]          = 64
#define OFF_WKT   62272      // [2][9][128][128] = 294912
#define OFF_PROJT 357184     // 187392 floats (8 transposed+padded proj mats)
#define OFF_OFFM  544576     // [16384][27]      = 442368
#define OFF_BUFA  986944     // [16384][128]     = 2097152
#define OFF_BUFB  3084096    // [16384][128]     = 2097152
#define OFF_STATS 5181248    // [10][2][128]     = 2560
#define WS_FLOATS 5183808    // ~20.7 MB

// ---------------------------------------------------------------------------
// Setup: compose [ow;mw] @ cw -> 27-ch conv weights (layout [k][o][c]),
// composed bias, and transpose cw -> wkT [k][c][o] for the deform matvec.
// PER-BLOCK sizes: wcomb = 9*27*128 = 31104 floats, bcomb = 27, wkT = 147456.
// ---------------------------------------------------------------------------
__global__ __launch_bounds__(256) void setup_conv(
    const float* __restrict__ cw, const float* __restrict__ cb,
    const float* __restrict__ ow, const float* __restrict__ mw,
    float* __restrict__ wcomb, float* __restrict__ bcomb,
    float* __restrict__ wkT)
{
    int tid = blockIdx.x * 256 + threadIdx.x;
    if (tid < 31104) {
        int c = tid & 127;
        int o = (tid >> 7) % 27;
        int k = tid / 3456;                  // k in [0,9)
        const float* sel = (o < 18) ? (ow + o * 128) : (mw + (o - 18) * 128);
        float v = 0.f;
        for (int cp = 0; cp < 128; ++cp)
            v = fmaf(sel[cp], cw[cp * 1152 + c * 9 + k], v);
        wcomb[tid] = v;                      // wcomb[k][o][c]
    } else if (tid < 31104 + 27) {
        int o = tid - 31104;
        const float* sel = (o < 18) ? (ow + o * 128) : (mw + (o - 18) * 128);
        float v = 0.f;
        for (int cp = 0; cp < 128; ++cp)
            v = fmaf(sel[cp], cb[cp], v);
        bcomb[o] = v;
    } else if (tid >= 32768 && tid < 32768 + 147456) {
        int i = tid - 32768;
        int o = i & 127;
        int c = (i >> 7) & 127;
        int k = i >> 14;
        wkT[i] = cw[o * 1152 + c * 9 + k];   // wkT[k][c][o]
    }
}

// Transpose the 8 projection matrices [O][128] -> padded [128][Opad],
// Opad = 8*ceil(O/8); pad entries zeroed so float4 weight loads are safe.
__global__ __launch_bounds__(256) void setup_proj(
    const float* __restrict__ s0, const float* __restrict__ s1,
    const float* __restrict__ s2, const float* __restrict__ s3,
    const float* __restrict__ s4, const float* __restrict__ s5,
    const float* __restrict__ s6, const float* __restrict__ s7,
    float* __restrict__ dst)
{
    const int Os[8]   = {20, 80, 150, 150, 210, 210, 308, 308};
    const int Op[8]   = {24, 80, 152, 152, 216, 216, 312, 312};
    const int offs[8] = {0, 3072, 13312, 32768, 52224, 79872, 107520, 147456};
    int tid = blockIdx.x * 256 + threadIdx.x;
    if (tid >= 187392) return;
    int m = 0;
    #pragma unroll
    for (int j = 1; j < 8; ++j) if (tid >= offs[j]) m = j;
    const float* src;
    switch (m) {
        case 0: src = s0; break; case 1: src = s1; break;
        case 2: src = s2; break; case 3: src = s3; break;
        case 4: src = s4; break; case 5: src = s5; break;
        case 6: src = s6; break; default: src = s7; break;
    }
    int i = tid - offs[m];
    int O = Os[m], Opad = Op[m];
    int c = i / Opad, o = i - c * Opad;
    dst[tid] = (o < O) ? src[o * 128 + c] : 0.f;
}

// ---------------------------------------------------------------------------
// conv_offm: 27-ch 3x3 conv per pixel + softmax(mask) -> offm[py9|px9|mask9]
// 2 waves/block, 4 pixels/wave; lanes split channels (c=lane, c=lane+64).
// ---------------------------------------------------------------------------
__global__ __launch_bounds__(128, 1) void conv_offm(
    const float* __restrict__ x, const float* __restrict__ wcomb,
    const float* __restrict__ bcomb, float* __restrict__ offm)
{
    const int lane = threadIdx.x & 63;
    const int wid  = threadIdx.x >> 6;
    const int gp0  = (blockIdx.x * 2 + wid) * 4;     // 4 consecutive pixels, same row
    const int h0   = gp0 >> 7;
    const int w0   = gp0 & 127;

    float acc[4][27];
    #pragma unroll
    for (int p = 0; p < 4; ++p)
        #pragma unroll
        for (int o = 0; o < 27; ++o) acc[p][o] = 0.f;

    for (int k = 0; k < 9; ++k) {
        const int dy = k / 3 - 1, dx = k % 3 - 1;
        const int ny = h0 + dy;
        float xv0[4], xv1[4];
        #pragma unroll
        for (int p = 0; p < 4; ++p) {
            const int nx = w0 + p + dx;
            const bool ok = (ny >= 0) & (ny < HH) & (nx >= 0) & (nx < WW);
            const float* xb = x + (((ny < 0 ? 0 : (ny > 127 ? 127 : ny)) << 7)
                                   + (nx < 0 ? 0 : (nx > 127 ? 127 : nx))) * 128;
            xv0[p] = ok ? xb[lane]      : 0.f;
            xv1[p] = ok ? xb[lane + 64] : 0.f;
        }
        const float* wb = wcomb + k * 27 * 128;
        #pragma unroll
        for (int o = 0; o < 27; ++o) {
            const float wv0 = wb[o * 128 + lane];
            const float wv1 = wb[o * 128 + 64 + lane];
            #pragma unroll
            for (int p = 0; p < 4; ++p)
                acc[p][o] = fmaf(xv0[p], wv0, fmaf(xv1[p], wv1, acc[p][o]));
        }
    }

    // cross-lane butterfly reduce each of the 108 partials
    #pragma unroll
    for (int p = 0; p < 4; ++p)
        #pragma unroll
        for (int o = 0; o < 27; ++o) {
            float v = acc[p][o];
            v += __shfl_xor(v, 32);
            v += __shfl_xor(v, 16);
            v += __shfl_xor(v, 8);
            v += __shfl_xor(v, 4);
            v += __shfl_xor(v, 2);
            v += __shfl_xor(v, 1);
            acc[p][o] = v;
        }

    #pragma unroll
    for (int p = 0; p < 4; ++p) {
        if (lane == p) {
            const int gp = gp0 + p;
            const int hh = gp >> 7, ww = gp & 127;
            float vals[27];
            #pragma unroll
            for (int o = 0; o < 27; ++o) vals[o] = acc[p][o] + bcomb[o];
            float mx = vals[18];
            #pragma unroll
            for (int k = 1; k < 9; ++k) mx = fmaxf(mx, vals[18 + k]);
            float e[9], se = 0.f;
            #pragma unroll
            for (int k = 0; k < 9; ++k) { e[k] = expf(vals[18 + k] - mx); se += e[k]; }
            const float inv = 1.f / se;
            float* ob = offm + gp * 27;
            #pragma unroll
            for (int k = 0; k < 9; ++k) {
                ob[k]      = (float)(hh - 1 + k / 3) + vals[2 * k];      // py
                ob[9 + k]  = (float)(ww - 1 + k % 3) + vals[2 * k + 1];  // px
                ob[18 + k] = e[k] * inv;                                 // mask
            }
        }
    }
}

// ---------------------------------------------------------------------------
// deform: bilinear gather (samp -> LDS, pixel-minor pack) + 128x1152 matvec.
// 4 waves/block, 8 pixels/block, 4-way split-K (288 kc each).
// LDS = 36864 B -> 4 blocks/CU -> 16 waves/CU (4/SIMD), 2x round-3 occupancy.
// Cross-wave partials recycle smA4's storage after a sync (no extra LDS).
// ---------------------------------------------------------------------------
__global__ __launch_bounds__(256, 1) void deform_kernel(
    const float* __restrict__ x, const float* __restrict__ offm,
    const float* __restrict__ wkT, const float* __restrict__ cb,
    float* __restrict__ y)
{
    __shared__ float4 smA4[1152];   // pixels 0..3, [kc][4]
    __shared__ float4 smB4[1152];   // pixels 4..7
    float* part = (float*)smA4;     // recycled for cross-wave partials (3072 floats)

    const int lane = threadIdx.x & 63;
    const int wid  = threadIdx.x >> 6;          // 0..3
    const int gp0  = blockIdx.x * 8;

    // ---- phase 1: wave wid gathers pixels [2*wid, 2*wid+2) ----
    {
        const int pxbase = 2 * wid;                       // 0,2,4,6
        float* smw = (pxbase < 4) ? (float*)smA4 : (float*)smB4;
        const int ppbase = pxbase & 3;                    // 0 or 2
        for (int pp = 0; pp < 2; ++pp) {
            const int gp = gp0 + pxbase + pp;
            const float* ob = offm + gp * 27;
            for (int k = 0; k < 9; ++k) {
                const float py = ob[k], px = ob[9 + k], mk = ob[18 + k];
                const float y0f = floorf(py), x0f = floorf(px);
                const int iy0 = (int)y0f, ix0 = (int)x0f;
                const float wy1 = py - y0f, wy0 = 1.f - wy1;
                const float wx1 = px - x0f, wx0 = 1.f - wx1;
                float s0 = 0.f, s1 = 0.f;
                #pragma unroll
                for (int cy = 0; cy < 2; ++cy) {
                    const int yy = iy0 + cy;
                    if (yy < 0 || yy > 127) continue;
                    const float wy = cy ? wy1 : wy0;
                    #pragma unroll
                    for (int cx = 0; cx < 2; ++cx) {
                        const int xx = ix0 + cx;
                        if (xx < 0 || xx > 127) continue;
                        const float wgt = wy * (cx ? wx1 : wx0);
                        const float* xb = x + (((yy << 7) + xx) << 7);
                        s0 = fmaf(wgt, xb[lane], s0);
                        s1 = fmaf(wgt, xb[lane + 64], s1);
                    }
                }
                smw[(k * 128 + lane) * 4 + ppbase + pp]      = s0 * mk;
                smw[(k * 128 + 64 + lane) * 4 + ppbase + pp] = s1 * mk;
            }
        }
    }
    __syncthreads();

    // ---- phase 2: wave wid handles kc in [wid*288, wid*288+288) ----
    float acc0[8], acc1[8];
    #pragma unroll
    for (int p = 0; p < 8; ++p) { acc0[p] = 0.f; acc1[p] = 0.f; }
    const int kc0 = wid * 288;
    const float* wp = wkT + kc0 * 128;
    #pragma unroll 2
    for (int i = 0; i < 288; ++i) {
        const float w0 = wp[i * 128 + lane];
        const float w1 = wp[i * 128 + 64 + lane];
        const float4 a = smA4[kc0 + i];
        const float4 b = smB4[kc0 + i];
        acc0[0] = fmaf(a.x, w0, acc0[0]); acc0[1] = fmaf(a.y, w0, acc0[1]);
        acc0[2] = fmaf(a.z, w0, acc0[2]); acc0[3] = fmaf(a.w, w0, acc0[3]);
        acc0[4] = fmaf(b.x, w0, acc0[4]); acc0[5] = fmaf(b.y, w0, acc0[5]);
        acc0[6] = fmaf(b.z, w0, acc0[6]); acc0[7] = fmaf(b.w, w0, acc0[7]);
        acc1[0] = fmaf(a.x, w1, acc1[0]); acc1[1] = fmaf(a.y, w1, acc1[1]);
        acc1[2] = fmaf(a.z, w1, acc1[2]); acc1[3] = fmaf(a.w, w1, acc1[3]);
        acc1[4] = fmaf(b.x, w1, acc1[4]); acc1[5] = fmaf(b.y, w1, acc1[5]);
        acc1[6] = fmaf(b.z, w1, acc1[6]); acc1[7] = fmaf(b.w, w1, acc1[7]);
    }
    __syncthreads();   // all phase-2 LDS reads done; smA4 storage now reusable

    if (wid != 0) {
        float* pb = part + (wid - 1) * 1024;
        #pragma unroll
        for (int p = 0; p < 8; ++p) {
            pb[p * 64 + lane]       = acc0[p];
            pb[512 + p * 64 + lane] = acc1[p];
        }
    }
    __syncthreads();
    if (wid == 0) {
        const float b0 = cb[lane], b1 = cb[lane + 64];
        #pragma unroll
        for (int p = 0; p < 8; ++p) {
            float v0 = acc0[p] + b0;
            float v1 = acc1[p] + b1;
            #pragma unroll
            for (int w = 0; w < 3; ++w) {
                v0 += part[w * 1024 + p * 64 + lane];
                v1 += part[w * 1024 + 512 + p * 64 + lane];
            }
            y[(gp0 + p) * 128 + lane]      = v0;
            y[(gp0 + p) * 128 + 64 + lane] = v1;
        }
    }
}

// ---------------------------------------------------------------------------
// Per-channel sum / sumsq over the image (for the BN-style normalization).
// ---------------------------------------------------------------------------
__global__ __launch_bounds__(256) void stats_kernel(
    const float* __restrict__ y, float* __restrict__ stats)
{
    const int g = blockIdx.x * 256 + threadIdx.x;   // grid 256 -> 65536 threads
    float s = 0.f, q = 0.f;
    for (int i = g; i < NELEM; i += 65536) {
        const float v = y[i];
        s += v;
        q = fmaf(v, v, q);
    }
    __shared__ float ls[256], lq[256];
    ls[threadIdx.x] = s; lq[threadIdx.x] = q;
    __syncthreads();
    if (threadIdx.x < 128) {
        atomicAdd(&stats[threadIdx.x],       ls[threadIdx.x] + ls[threadIdx.x + 128]);
        atomicAdd(&stats[128 + threadIdx.x], lq[threadIdx.x] + lq[threadIdx.x + 128]);
    }
}

__global__ __launch_bounds__(256) void norm_relu(
    float* __restrict__ y, const float* __restrict__ stats,
    const float* __restrict__ bg, const float* __restrict__ bb)
{
    const int g = blockIdx.x * 256 + threadIdx.x;
    const int c = g & 127;
    const float mean = stats[c] * (1.f / 16384.f);
    const float var  = stats[128 + c] * (1.f / 16384.f) - mean * mean;
    const float rstd = rsqrtf(var + EPS);
    const float scale = bg[c] * rstd;
    const float shift = bb[c] - mean * scale;
    for (int i = g; i < NELEM; i += 65536)
        y[i] = fmaxf(fmaf(y[i], scale, shift), 0.f);
}

// ---------------------------------------------------------------------------
// 1x1 projection, register-blocked tile GEMM.
// Grid (256 pixel-tiles, ceil(O/32)); 4 waves/block; each wave computes 8
// consecutive outputs over a 64-pixel LDS tile (stride 129, conflict-free).
// Weights are padded [c][Opad] so per-c fetch = two broadcast float4 loads.
// ---------------------------------------------------------------------------
__global__ __launch_bounds__(256) void proj_kernel(
    const float* __restrict__ xin, const float* __restrict__ wT,
    float* __restrict__ out, int O, int Opad, int accum)
{
    __shared__ float tile[64 * 129];
    const int gp0 = blockIdx.x * 64;
    for (int i = threadIdx.x; i < 8192; i += 256) {
        const int p = i >> 7, c = i & 127;
        tile[p * 129 + c] = xin[(gp0 + p) * 128 + c];
    }
    __syncthreads();

    const int p  = threadIdx.x & 63;
    const int wv = threadIdx.x >> 6;
    const int ob = blockIdx.y * 32 + wv * 8;
    if (ob >= O) return;

    const float* row = tile + p * 129;
    const float* wp  = wT + ob;
    float acc[8] = {0.f, 0.f, 0.f, 0.f, 0.f, 0.f, 0.f, 0.f};
    #pragma unroll 4
    for (int c = 0; c < 128; ++c) {
        const float  v  = row[c];
        const float4 w0 = *(const float4*)(wp + c * Opad);
        const float4 w1 = *(const float4*)(wp + c * Opad + 4);
        acc[0] = fmaf(v, w0.x, acc[0]); acc[1] = fmaf(v, w0.y, acc[1]);
        acc[2] = fmaf(v, w0.z, acc[2]); acc[3] = fmaf(v, w0.w, acc[3]);
        acc[4] = fmaf(v, w1.x, acc[4]); acc[5] = fmaf(v, w1.y, acc[5]);
        acc[6] = fmaf(v, w1.z, acc[6]); acc[7] = fmaf(v, w1.w, acc[7]);
    }
    #pragma unroll
    for (int j = 0; j < 8; ++j) {
        if (ob + j < O) {
            float* dst = out + (size_t)(ob + j) * NPIX + gp0 + p;
            *dst = accum ? (*dst + acc[j]) : acc[j];
        }
    }
}

// ---------------------------------------------------------------------------
// Final layernorm over the W axis: one wave per (c,h) row of 128.
// ---------------------------------------------------------------------------
__global__ __launch_bounds__(256) void final_ln(
    float* __restrict__ out, const float* __restrict__ lnw,
    const float* __restrict__ lnb)
{
    const int lane = threadIdx.x & 63;
    const int wid  = threadIdx.x >> 6;
    const int row  = blockIdx.x * 4 + wid;          // 98304 rows
    float* rp = out + row * 128;
    const float v0 = rp[lane], v1 = rp[lane + 64];
    float s = v0 + v1;
    float q = v0 * v0 + v1 * v1;
    #pragma unroll
    for (int m = 32; m; m >>= 1) {
        s += __shfl_xor(s, m);
        q += __shfl_xor(q, m);
    }
    const float mean = s * (1.f / 128.f);
    const float var  = q * (1.f / 128.f) - mean * mean;
    const float rstd = rsqrtf(var + EPS);
    rp[lane]      = (v0 - mean) * rstd * lnw[lane]      + lnb[lane];
    rp[lane + 64] = (v1 - mean) * rstd * lnw[lane + 64] + lnb[lane + 64];
}

// ---------------------------------------------------------------------------
extern "C" void kernel_launch(void* const* d_in, const int* in_sizes, int n_in,
                              void* d_out, int out_size, void* d_ws, size_t ws_size,
                              hipStream_t stream)
{
    const float* xin[5];
    for (int i = 0; i < 5; ++i) xin[i] = (const float*)d_in[i];
    const float* b_cw[2] = {(const float*)d_in[5],  (const float*)d_in[11]};
    const float* b_cb[2] = {(const float*)d_in[6],  (const float*)d_in[12]};
    const float* b_ow[2] = {(const float*)d_in[7],  (const float*)d_in[13]};
    const float* b_mw[2] = {(const float*)d_in[8],  (const float*)d_in[14]};
    const float* b_bg[2] = {(const float*)d_in[9],  (const float*)d_in[15]};
    const float* b_bb[2] = {(const float*)d_in[10], (const float*)d_in[16]};
    const float* pw[8];
    for (int i = 0; i < 8; ++i) pw[i] = (const float*)d_in[17 + i];
    const float* lnw = (const float*)d_in[25];
    const float* lnb = (const float*)d_in[26];

    float* W = (float*)d_ws;
    float* out = (float*)d_out;

    hipMemsetAsync(W + OFF_STATS, 0, 2560 * sizeof(float), stream);

    setup_conv<<<704, 256, 0, stream>>>(b_cw[0], b_cb[0], b_ow[0], b_mw[0],
        W + OFF_WCOMB, W + OFF_BCOMB, W + OFF_WKT);
    setup_conv<<<704, 256, 0, stream>>>(b_cw[1], b_cb[1], b_ow[1], b_mw[1],
        W + OFF_WCOMB + 31104, W + OFF_BCOMB + 32, W + OFF_WKT + 147456);
    setup_proj<<<732, 256, 0, stream>>>(pw[0], pw[1], pw[2], pw[3],
        pw[4], pw[5], pw[6], pw[7], W + OFF_PROJT);

    static const int Obase[5]  = {0, 20, 100, 250, 460};
    static const int Ocnt[5]   = {20, 80, 150, 210, 308};
    static const int Opad5[5]  = {24, 80, 152, 216, 312};
    static const int taOff[5]  = {0, 3072, 13312, 52224, 107520};   // c1w,c2w,c3aw,c4aw,c5aw
    static const int tbOff[5]  = {0, 0, 32768, 79872, 147456};      // c3bw,c4bw,c5bw

    for (int img = 0; img < 5; ++img) {
        for (int blk = 0; blk < 2; ++blk) {
            const float* xb = (blk == 0) ? xin[img] : (W + OFF_BUFA);
            float* yb = (blk == 0) ? (W + OFF_BUFA) : (W + OFF_BUFB);
            conv_offm<<<2048, 128, 0, stream>>>(
                xb, W + OFF_WCOMB + blk * 31104, W + OFF_BCOMB + blk * 32,
                W + OFF_OFFM);
            deform_kernel<<<2048, 256, 0, stream>>>(
                xb, W + OFF_OFFM, W + OFF_WKT + blk * 147456, b_cb[blk], yb);
            float* st = W + OFF_STATS + (img * 2 + blk) * 256;
            stats_kernel<<<256, 256, 0, stream>>>(yb, st);
            norm_relu<<<256, 256, 0, stream>>>(yb, st, b_bg[blk], b_bb[blk]);
        }
        float* outb = out + (size_t)Obase[img] * NPIX;
        const int oTiles = (Ocnt[img] + 31) / 32;
        proj_kernel<<<dim3(256, oTiles), 256, 0, stream>>>(
            W + OFF_BUFB, W + OFF_PROJT + taOff[img], outb,
            Ocnt[img], Opad5[img], 0);
        if (img >= 2)
            proj_kernel<<<dim3(256, oTiles), 256, 0, stream>>>(
                xin[img], W + OFF_PROJT + tbOff[img], outb,
                Ocnt[img], Opad5[img], 1);
    }
    final_ln<<<24576, 256, 0, stream>>>(out, lnw, lnb);
}

// Round 5
// 1738.711 us; speedup vs baseline: 2.8082x; 1.3157x over previous
//
#include <hip/hip_runtime.h>
#include <math.h>

// Problem constants
#define HH 128
#define WW 128
#define CC 128
#define KK 9
#define NPIX 16384           // H*W
#define NELEM 2097152        // NPIX*C
#define EPS 1e-5f

// Workspace layout (float offsets)
#define OFF_WCOMB 0          // [2][9][27][128]  = 62208
#define OFF_BCOMB 62208      // [2][32]          = 64
#define OFF_WB    62272      // bf16 B-fragment weights: 2*147456 ushort = 147456 floats
#define OFF_PROJT 209728     // 187392 floats (8 transposed+padded proj mats)
#define OFF_OFFM  397120     // [16384][27]      = 442368
#define OFF_BUFA  839488     // [16384][128]     = 2097152
#define OFF_BUFB  2936640    // [16384][128]     = 2097152
#define OFF_STATS 5033792    // [10][2][128]     = 2560
#define WS_FLOATS 5036352    // ~20.1 MB

typedef __bf16 bf16x8 __attribute__((ext_vector_type(8)));
typedef float  floatx4 __attribute__((ext_vector_type(4)));

__device__ __forceinline__ unsigned short f2bf(float f) {
    unsigned u = __float_as_uint(f);
    return (unsigned short)((u + 0x7FFF + ((u >> 16) & 1)) >> 16);   // RNE
}

// ---------------------------------------------------------------------------
// Setup: compose [ow;mw] @ cw -> 27-ch conv weights (layout [k][o][c]),
// composed bias, and swizzle cw into bf16 MFMA B-fragment order:
//   wB[s][t][lane][j] = bf16(cw[o*1152 + c*9 + k])
//   kc = s*32 + (lane>>4)*8 + j (kc = k*128+c), o = t*16 + (lane&15)
// PER-BLOCK: wcomb = 31104 floats, bcomb = 27, wB = 147456 ushorts.
// ---------------------------------------------------------------------------
__global__ __launch_bounds__(256) void setup_conv(
    const float* __restrict__ cw, const float* __restrict__ cb,
    const float* __restrict__ ow, const float* __restrict__ mw,
    float* __restrict__ wcomb, float* __restrict__ bcomb,
    unsigned short* __restrict__ wBu)
{
    int tid = blockIdx.x * 256 + threadIdx.x;
    if (tid < 31104) {
        int c = tid & 127;
        int o = (tid >> 7) % 27;
        int k = tid / 3456;                  // k in [0,9)
        const float* sel = (o < 18) ? (ow + o * 128) : (mw + (o - 18) * 128);
        float v = 0.f;
        for (int cp = 0; cp < 128; ++cp)
            v = fmaf(sel[cp], cw[cp * 1152 + c * 9 + k], v);
        wcomb[tid] = v;                      // wcomb[k][o][c]
    } else if (tid < 31104 + 27) {
        int o = tid - 31104;
        const float* sel = (o < 18) ? (ow + o * 128) : (mw + (o - 18) * 128);
        float v = 0.f;
        for (int cp = 0; cp < 128; ++cp)
            v = fmaf(sel[cp], cb[cp], v);
        bcomb[o] = v;
    } else if (tid >= 32768 && tid < 32768 + 147456) {
        int i = tid - 32768;
        int j    = i & 7;
        int lane = (i >> 3) & 63;
        int t    = (i >> 9) & 7;
        int s    = i >> 12;                  // 0..35
        int kc   = s * 32 + ((lane >> 4) << 3) + j;
        int o    = t * 16 + (lane & 15);
        wBu[i] = f2bf(cw[o * 1152 + (kc & 127) * 9 + (kc >> 7)]);
    }
}

// Transpose the 8 projection matrices [O][128] -> padded [128][Opad],
// Opad = 8*ceil(O/8); pad entries zeroed so float4 weight loads are safe.
__global__ __launch_bounds__(256) void setup_proj(
    const float* __restrict__ s0, const float* __restrict__ s1,
    const float* __restrict__ s2, const float* __restrict__ s3,
    const float* __restrict__ s4, const float* __restrict__ s5,
    const float* __restrict__ s6, const float* __restrict__ s7,
    float* __restrict__ dst)
{
    const int Os[8]   = {20, 80, 150, 150, 210, 210, 308, 308};
    const int Op[8]   = {24, 80, 152, 152, 216, 216, 312, 312};
    const int offs[8] = {0, 3072, 13312, 32768, 52224, 79872, 107520, 147456};
    int tid = blockIdx.x * 256 + threadIdx.x;
    if (tid >= 187392) return;
    int m = 0;
    #pragma unroll
    for (int j = 1; j < 8; ++j) if (tid >= offs[j]) m = j;
    const float* src;
    switch (m) {
        case 0: src = s0; break; case 1: src = s1; break;
        case 2: src = s2; break; case 3: src = s3; break;
        case 4: src = s4; break; case 5: src = s5; break;
        case 6: src = s6; break; default: src = s7; break;
    }
    int i = tid - offs[m];
    int O = Os[m], Opad = Op[m];
    int c = i / Opad, o = i - c * Opad;
    dst[tid] = (o < O) ? src[o * 128 + c] : 0.f;
}

// ---------------------------------------------------------------------------
// conv_offm: 27-ch 3x3 conv per pixel + softmax(mask) -> offm[py9|px9|mask9]
// 2 waves/block, 4 pixels/wave; lanes split channels (c=lane, c=lane+64).
// ---------------------------------------------------------------------------
__global__ __launch_bounds__(128, 1) void conv_offm(
    const float* __restrict__ x, const float* __restrict__ wcomb,
    const float* __restrict__ bcomb, float* __restrict__ offm)
{
    const int lane = threadIdx.x & 63;
    const int wid  = threadIdx.x >> 6;
    const int gp0  = (blockIdx.x * 2 + wid) * 4;     // 4 consecutive pixels, same row
    const int h0   = gp0 >> 7;
    const int w0   = gp0 & 127;

    float acc[4][27];
    #pragma unroll
    for (int p = 0; p < 4; ++p)
        #pragma unroll
        for (int o = 0; o < 27; ++o) acc[p][o] = 0.f;

    for (int k = 0; k < 9; ++k) {
        const int dy = k / 3 - 1, dx = k % 3 - 1;
        const int ny = h0 + dy;
        float xv0[4], xv1[4];
        #pragma unroll
        for (int p = 0; p < 4; ++p) {
            const int nx = w0 + p + dx;
            const bool ok = (ny >= 0) & (ny < HH) & (nx >= 0) & (nx < WW);
            const float* xb = x + (((ny < 0 ? 0 : (ny > 127 ? 127 : ny)) << 7)
                                   + (nx < 0 ? 0 : (nx > 127 ? 127 : nx))) * 128;
            xv0[p] = ok ? xb[lane]      : 0.f;
            xv1[p] = ok ? xb[lane + 64] : 0.f;
        }
        const float* wb = wcomb + k * 27 * 128;
        #pragma unroll
        for (int o = 0; o < 27; ++o) {
            const float wv0 = wb[o * 128 + lane];
            const float wv1 = wb[o * 128 + 64 + lane];
            #pragma unroll
            for (int p = 0; p < 4; ++p)
                acc[p][o] = fmaf(xv0[p], wv0, fmaf(xv1[p], wv1, acc[p][o]));
        }
    }

    // cross-lane butterfly reduce each of the 108 partials
    #pragma unroll
    for (int p = 0; p < 4; ++p)
        #pragma unroll
        for (int o = 0; o < 27; ++o) {
            float v = acc[p][o];
            v += __shfl_xor(v, 32);
            v += __shfl_xor(v, 16);
            v += __shfl_xor(v, 8);
            v += __shfl_xor(v, 4);
            v += __shfl_xor(v, 2);
            v += __shfl_xor(v, 1);
            acc[p][o] = v;
        }

    #pragma unroll
    for (int p = 0; p < 4; ++p) {
        if (lane == p) {
            const int gp = gp0 + p;
            const int hh = gp >> 7, ww = gp & 127;
            float vals[27];
            #pragma unroll
            for (int o = 0; o < 27; ++o) vals[o] = acc[p][o] + bcomb[o];
            float mx = vals[18];
            #pragma unroll
            for (int k = 1; k < 9; ++k) mx = fmaxf(mx, vals[18 + k]);
            float e[9], se = 0.f;
            #pragma unroll
            for (int k = 0; k < 9; ++k) { e[k] = expf(vals[18 + k] - mx); se += e[k]; }
            const float inv = 1.f / se;
            float* ob = offm + gp * 27;
            #pragma unroll
            for (int k = 0; k < 9; ++k) {
                ob[k]      = (float)(hh - 1 + k / 3) + vals[2 * k];      // py
                ob[9 + k]  = (float)(ww - 1 + k % 3) + vals[2 * k + 1];  // px
                ob[18 + k] = e[k] * inv;                                 // mask
            }
        }
    }
}

// ---------------------------------------------------------------------------
// deform: bilinear gather -> bf16 LDS, then MFMA 16x16x32 bf16 GEMM.
// 16 px/block, 4 waves. LDS rows padded to 1160 bf16 (stride 580 dwords,
// =4 mod 32 -> A-frag ds_read_b128 is 2-way = conflict-free).
// Gather: lane = channel pair (2l, 2l+1), one float2 load per corner,
// RNE-pack to bf16x2, single ds_write_b32 (stride-1).
// MFMA: A[m=lane&15][k=quad*8+j] from LDS; B pre-swizzled fragment order
// (one dwordx4 per frag); D col=lane&15, row=quad*4+reg.
// ---------------------------------------------------------------------------
__global__ __launch_bounds__(256, 1) void deform_kernel(
    const float* __restrict__ x, const float* __restrict__ offm,
    const unsigned short* __restrict__ wBu, const float* __restrict__ cb,
    float* __restrict__ y)
{
    __shared__ unsigned short smp[16 * 1160];   // 37120 B -> 4 blocks/CU

    const int lane = threadIdx.x & 63;
    const int wid  = threadIdx.x >> 6;          // 0..3
    const int gp0  = blockIdx.x * 16;

    // ---- phase 1: wave wid gathers pixels [4*wid, 4*wid+4) ----
    for (int pp = 0; pp < 4; ++pp) {
        const int pl = wid * 4 + pp;            // 0..15
        const float* ob = offm + (gp0 + pl) * 27;
        unsigned* dst = (unsigned*)smp + pl * 580 + lane;
        for (int k = 0; k < 9; ++k) {
            const float py = ob[k], px = ob[9 + k], mk = ob[18 + k];
            const float y0f = floorf(py), x0f = floorf(px);
            const int iy0 = (int)y0f, ix0 = (int)x0f;
            const float wy1 = py - y0f, wy0 = 1.f - wy1;
            const float wx1 = px - x0f, wx0 = 1.f - wx1;
            float s0 = 0.f, s1 = 0.f;
            #pragma unroll
            for (int cy = 0; cy < 2; ++cy) {
                const int yy = iy0 + cy;
                if (yy < 0 || yy > 127) continue;
                const float wy = cy ? wy1 : wy0;
                #pragma unroll
                for (int cx = 0; cx < 2; ++cx) {
                    const int xx = ix0 + cx;
                    if (xx < 0 || xx > 127) continue;
                    const float wgt = wy * (cx ? wx1 : wx0);
                    const float2 v = ((const float2*)(x + (((yy << 7) + xx) << 7)))[lane];
                    s0 = fmaf(wgt, v.x, s0);
                    s1 = fmaf(wgt, v.y, s1);
                }
            }
            s0 *= mk; s1 *= mk;
            dst[k * 64] = (unsigned)f2bf(s0) | ((unsigned)f2bf(s1) << 16);
        }
    }
    __syncthreads();

    // ---- phase 2: MFMA. wave wid handles out-tiles t = 2*wid, 2*wid+1 ----
    floatx4 acc0 = {0.f, 0.f, 0.f, 0.f};
    floatx4 acc1 = {0.f, 0.f, 0.f, 0.f};
    const int mrow = lane & 15;
    const int quad = lane >> 4;
    const unsigned short* arow = smp + mrow * 1160 + quad * 8;
    const int t0 = wid * 2, t1 = wid * 2 + 1;
    #pragma unroll 4
    for (int s = 0; s < 36; ++s) {
        const bf16x8 a  = *(const bf16x8*)(arow + s * 32);
        const bf16x8 b0 = *(const bf16x8*)(wBu + (((s * 8 + t0) * 64 + lane) << 3));
        const bf16x8 b1 = *(const bf16x8*)(wBu + (((s * 8 + t1) * 64 + lane) << 3));
        acc0 = __builtin_amdgcn_mfma_f32_16x16x32_bf16(a, b0, acc0, 0, 0, 0);
        acc1 = __builtin_amdgcn_mfma_f32_16x16x32_bf16(a, b1, acc1, 0, 0, 0);
    }

    // ---- epilogue: D col=lane&15, row=quad*4+reg; add conv bias ----
    const int n0 = t0 * 16 + mrow, n1 = t1 * 16 + mrow;
    const float bias0 = cb[n0], bias1 = cb[n1];
    #pragma unroll
    for (int r = 0; r < 4; ++r) {
        float* yr = y + (size_t)(gp0 + quad * 4 + r) * 128;
        yr[n0] = acc0[r] + bias0;
        yr[n1] = acc1[r] + bias1;
    }
}

// ---------------------------------------------------------------------------
// Per-channel sum / sumsq over the image (for the BN-style normalization).
// ---------------------------------------------------------------------------
__global__ __launch_bounds__(256) void stats_kernel(
    const float* __restrict__ y, float* __restrict__ stats)
{
    const int g = blockIdx.x * 256 + threadIdx.x;   // grid 256 -> 65536 threads
    float s = 0.f, q = 0.f;
    for (int i = g; i < NELEM; i += 65536) {
        const float v = y[i];
        s += v;
        q = fmaf(v, v, q);
    }
    __shared__ float ls[256], lq[256];
    ls[threadIdx.x] = s; lq[threadIdx.x] = q;
    __syncthreads();
    if (threadIdx.x < 128) {
        atomicAdd(&stats[threadIdx.x],       ls[threadIdx.x] + ls[threadIdx.x + 128]);
        atomicAdd(&stats[128 + threadIdx.x], lq[threadIdx.x] + lq[threadIdx.x + 128]);
    }
}

__global__ __launch_bounds__(256) void norm_relu(
    float* __restrict__ y, const float* __restrict__ stats,
    const float* __restrict__ bg, const float* __restrict__ bb)
{
    const int g = blockIdx.x * 256 + threadIdx.x;
    const int c = g & 127;
    const float mean = stats[c] * (1.f / 16384.f);
    const float var  = stats[128 + c] * (1.f / 16384.f) - mean * mean;
    const float rstd = rsqrtf(var + EPS);
    const float scale = bg[c] * rstd;
    const float shift = bb[c] - mean * scale;
    for (int i = g; i < NELEM; i += 65536)
        y[i] = fmaxf(fmaf(y[i], scale, shift), 0.f);
}

// ---------------------------------------------------------------------------
// 1x1 projection, register-blocked tile GEMM.
// Grid (256 pixel-tiles, ceil(O/32)); 4 waves/block; each wave computes 8
// consecutive outputs over a 64-pixel LDS tile (stride 129, conflict-free).
// Weights are padded [c][Opad] so per-c fetch = two broadcast float4 loads.
// ---------------------------------------------------------------------------
__global__ __launch_bounds__(256) void proj_kernel(
    const float* __restrict__ xin, const float* __restrict__ wT,
    float* __restrict__ out, int O, int Opad, int accum)
{
    __shared__ float tile[64 * 129];
    const int gp0 = blockIdx.x * 64;
    for (int i = threadIdx.x; i < 8192; i += 256) {
        const int p = i >> 7, c = i & 127;
        tile[p * 129 + c] = xin[(gp0 + p) * 128 + c];
    }
    __syncthreads();

    const int p  = threadIdx.x & 63;
    const int wv = threadIdx.x >> 6;
    const int ob = blockIdx.y * 32 + wv * 8;
    if (ob >= O) return;

    const float* row = tile + p * 129;
    const float* wp  = wT + ob;
    float acc[8] = {0.f, 0.f, 0.f, 0.f, 0.f, 0.f, 0.f, 0.f};
    #pragma unroll 4
    for (int c = 0; c < 128; ++c) {
        const float  v  = row[c];
        const float4 w0 = *(const float4*)(wp + c * Opad);
        const float4 w1 = *(const float4*)(wp + c * Opad + 4);
        acc[0] = fmaf(v, w0.x, acc[0]); acc[1] = fmaf(v, w0.y, acc[1]);
        acc[2] = fmaf(v, w0.z, acc[2]); acc[3] = fmaf(v, w0.w, acc[3]);
        acc[4] = fmaf(v, w1.x, acc[4]); acc[5] = fmaf(v, w1.y, acc[5]);
        acc[6] = fmaf(v, w1.z, acc[6]); acc[7] = fmaf(v, w1.w, acc[7]);
    }
    #pragma unroll
    for (int j = 0; j < 8; ++j) {
        if (ob + j < O) {
            float* dst = out + (size_t)(ob + j) * NPIX + gp0 + p;
            *dst = accum ? (*dst + acc[j]) : acc[j];
        }
    }
}

// ---------------------------------------------------------------------------
// Final layernorm over the W axis: one wave per (c,h) row of 128.
// ---------------------------------------------------------------------------
__global__ __launch_bounds__(256) void final_ln(
    float* __restrict__ out, const float* __restrict__ lnw,
    const float* __restrict__ lnb)
{
    const int lane = threadIdx.x & 63;
    const int wid  = threadIdx.x >> 6;
    const int row  = blockIdx.x * 4 + wid;          // 98304 rows
    float* rp = out + row * 128;
    const float v0 = rp[lane], v1 = rp[lane + 64];
    float s = v0 + v1;
    float q = v0 * v0 + v1 * v1;
    #pragma unroll
    for (int m = 32; m; m >>= 1) {
        s += __shfl_xor(s, m);
        q += __shfl_xor(q, m);
    }
    const float mean = s * (1.f / 128.f);
    const float var  = q * (1.f / 128.f) - mean * mean;
    const float rstd = rsqrtf(var + EPS);
    rp[lane]      = (v0 - mean) * rstd * lnw[lane]      + lnb[lane];
    rp[lane + 64] = (v1 - mean) * rstd * lnw[lane + 64] + lnb[lane + 64];
}

// ---------------------------------------------------------------------------
extern "C" void kernel_launch(void* const* d_in, const int* in_sizes, int n_in,
                              void* d_out, int out_size, void* d_ws, size_t ws_size,
                              hipStream_t stream)
{
    const float* xin[5];
    for (int i = 0; i < 5; ++i) xin[i] = (const float*)d_in[i];
    const float* b_cw[2] = {(const float*)d_in[5],  (const float*)d_in[11]};
    const float* b_cb[2] = {(const float*)d_in[6],  (const float*)d_in[12]};
    const float* b_ow[2] = {(const float*)d_in[7],  (const float*)d_in[13]};
    const float* b_mw[2] = {(const float*)d_in[8],  (const float*)d_in[14]};
    const float* b_bg[2] = {(const float*)d_in[9],  (const float*)d_in[15]};
    const float* b_bb[2] = {(const float*)d_in[10], (const float*)d_in[16]};
    const float* pw[8];
    for (int i = 0; i < 8; ++i) pw[i] = (const float*)d_in[17 + i];
    const float* lnw = (const float*)d_in[25];
    const float* lnb = (const float*)d_in[26];

    float* W = (float*)d_ws;
    float* out = (float*)d_out;
    unsigned short* wB = (unsigned short*)(W + OFF_WB);

    hipMemsetAsync(W + OFF_STATS, 0, 2560 * sizeof(float), stream);

    setup_conv<<<704, 256, 0, stream>>>(b_cw[0], b_cb[0], b_ow[0], b_mw[0],
        W + OFF_WCOMB, W + OFF_BCOMB, wB);
    setup_conv<<<704, 256, 0, stream>>>(b_cw[1], b_cb[1], b_ow[1], b_mw[1],
        W + OFF_WCOMB + 31104, W + OFF_BCOMB + 32, wB + 147456);
    setup_proj<<<732, 256, 0, stream>>>(pw[0], pw[1], pw[2], pw[3],
        pw[4], pw[5], pw[6], pw[7], W + OFF_PROJT);

    static const int Obase[5]  = {0, 20, 100, 250, 460};
    static const int Ocnt[5]   = {20, 80, 150, 210, 308};
    static const int Opad5[5]  = {24, 80, 152, 216, 312};
    static const int taOff[5]  = {0, 3072, 13312, 52224, 107520};   // c1w,c2w,c3aw,c4aw,c5aw
    static const int tbOff[5]  = {0, 0, 32768, 79872, 147456};      // c3bw,c4bw,c5bw

    for (int img = 0; img < 5; ++img) {
        for (int blk = 0; blk < 2; ++blk) {
            const float* xb = (blk == 0) ? xin[img] : (W + OFF_BUFA);
            float* yb = (blk == 0) ? (W + OFF_BUFA) : (W + OFF_BUFB);
            conv_offm<<<2048, 128, 0, stream>>>(
                xb, W + OFF_WCOMB + blk * 31104, W + OFF_BCOMB + blk * 32,
                W + OFF_OFFM);
            deform_kernel<<<1024, 256, 0, stream>>>(
                xb, W + OFF_OFFM, wB + blk * 147456, b_cb[blk], yb);
            float* st = W + OFF_STATS + (img * 2 + blk) * 256;
            stats_kernel<<<256, 256, 0, stream>>>(yb, st);
            norm_relu<<<256, 256, 0, stream>>>(yb, st, b_bg[blk], b_bb[blk]);
        }
        float* outb = out + (size_t)Obase[img] * NPIX;
        const int oTiles = (Ocnt[img] + 31) / 32;
        proj_kernel<<<dim3(256, oTiles), 256, 0, stream>>>(
            W + OFF_BUFB, W + OFF_PROJT + taOff[img], outb,
            Ocnt[img], Opad5[img], 0);
        if (img >= 2)
            proj_kernel<<<dim3(256, oTiles), 256, 0, stream>>>(
                xin[img], W + OFF_PROJT + tbOff[img], outb,
                Ocnt[img], Opad5[img], 1);
    }
    final_ln<<<24576, 256, 0, stream>>>(out, lnw, lnb);
}

// Round 6
// 1470.478 us; speedup vs baseline: 3.3204x; 1.1824x over previous
//
#include <hip/hip_runtime.h>
#include <math.h>

// Problem constants
#define HH 128
#define WW 128
#define CC 128
#define KK 9
#define NPIX 16384           // H*W
#define NELEM 2097152        // NPIX*C
#define EPS 1e-5f

// Workspace layout (float offsets)
#define OFF_WCOMB 0          // [2][9][27][128]  = 62208
#define OFF_BCOMB 62208      // [2][32]          = 64
#define OFF_WB    62272      // bf16 B-frag deform weights: 2*147456 ushort = 147456 floats
#define OFF_APROJ 209728     // hi/lo bf16 A-frag proj weights: 389120 ushort = 194560 floats
#define OFF_OFFM  404288     // [16384][27]      = 442368
#define OFF_BUFA  846656     // [16384][128]     = 2097152
#define OFF_BUFB  2943808    // [16384][128]     = 2097152
#define OFF_STATS 5040960    // [10][2][128]     = 2560
#define WS_FLOATS 5043520    // ~20.2 MB

typedef __bf16 bf16x8 __attribute__((ext_vector_type(8)));
typedef float  floatx4 __attribute__((ext_vector_type(4)));

__device__ __forceinline__ unsigned short f2bf(float f) {
    unsigned u = __float_as_uint(f);
    return (unsigned short)((u + 0x7FFF + ((u >> 16) & 1)) >> 16);   // RNE
}
__device__ __forceinline__ float bf2f(unsigned short h) {
    return __uint_as_float(((unsigned)h) << 16);
}

// ---------------------------------------------------------------------------
// Setup: compose [ow;mw] @ cw -> 27-ch conv weights (layout [k][o][c]),
// composed bias, and swizzle cw into bf16 MFMA B-fragment order:
//   kc = s*32 + (lane>>4)*8 + j (kc = k*128+c), o = t*16 + (lane&15)
// PER-BLOCK: wcomb = 31104 floats, bcomb = 27, wB = 147456 ushorts.
// ---------------------------------------------------------------------------
__global__ __launch_bounds__(256) void setup_conv(
    const float* __restrict__ cw, const float* __restrict__ cb,
    const float* __restrict__ ow, const float* __restrict__ mw,
    float* __restrict__ wcomb, float* __restrict__ bcomb,
    unsigned short* __restrict__ wBu)
{
    int tid = blockIdx.x * 256 + threadIdx.x;
    if (tid < 31104) {
        int c = tid & 127;
        int o = (tid >> 7) % 27;
        int k = tid / 3456;                  // k in [0,9)
        const float* sel = (o < 18) ? (ow + o * 128) : (mw + (o - 18) * 128);
        float v = 0.f;
        for (int cp = 0; cp < 128; ++cp)
            v = fmaf(sel[cp], cw[cp * 1152 + c * 9 + k], v);
        wcomb[tid] = v;                      // wcomb[k][o][c]
    } else if (tid < 31104 + 27) {
        int o = tid - 31104;
        const float* sel = (o < 18) ? (ow + o * 128) : (mw + (o - 18) * 128);
        float v = 0.f;
        for (int cp = 0; cp < 128; ++cp)
            v = fmaf(sel[cp], cb[cp], v);
        bcomb[o] = v;
    } else if (tid >= 32768 && tid < 32768 + 147456) {
        int i = tid - 32768;
        int j    = i & 7;
        int lane = (i >> 3) & 63;
        int t    = (i >> 9) & 7;
        int s    = i >> 12;                  // 0..35
        int kc   = s * 32 + ((lane >> 4) << 3) + j;
        int o    = t * 16 + (lane & 15);
        wBu[i] = f2bf(cw[o * 1152 + (kc & 127) * 9 + (kc >> 7)]);
    }
}

// ---------------------------------------------------------------------------
// Swizzle 8 projection matrices [O][128] into hi/lo bf16 A-fragment planes.
// A[m=o_in_tile][k=c]: o = ot*16 + (lane&15), c = s*32 + (lane>>4)*8 + j.
// Per matrix: hi plane nOt*2048 ushorts, lo plane follows at +nOt*2048.
// ---------------------------------------------------------------------------
__global__ __launch_bounds__(256) void setup_projA(
    const float* __restrict__ s0, const float* __restrict__ s1,
    const float* __restrict__ s2, const float* __restrict__ s3,
    const float* __restrict__ s4, const float* __restrict__ s5,
    const float* __restrict__ s6, const float* __restrict__ s7,
    unsigned short* __restrict__ dst)
{
    const int Os[8]   = {20, 80, 150, 150, 210, 210, 308, 308};
    const int nOt[8]  = {2, 5, 10, 10, 14, 14, 20, 20};
    const int tOff[8] = {0, 4096, 14336, 34816, 55296, 83968, 112640, 153600};
    const int dOff[8] = {0, 8192, 28672, 69632, 110592, 167936, 225280, 307200};
    int tid = blockIdx.x * 256 + threadIdx.x;
    if (tid >= 194560) return;
    int m = 0;
    #pragma unroll
    for (int q = 1; q < 8; ++q) if (tid >= tOff[q]) m = q;
    const float* src;
    switch (m) {
        case 0: src = s0; break; case 1: src = s1; break;
        case 2: src = s2; break; case 3: src = s3; break;
        case 4: src = s4; break; case 5: src = s5; break;
        case 6: src = s6; break; default: src = s7; break;
    }
    int i = tid - tOff[m];
    int j    = i & 7;
    int lane = (i >> 3) & 63;
    int s    = (i >> 9) & 3;
    int ot   = i >> 11;
    int o = ot * 16 + (lane & 15);
    int c = s * 32 + ((lane >> 4) << 3) + j;
    float v = (o < Os[m]) ? src[o * 128 + c] : 0.f;
    unsigned short h = f2bf(v);
    unsigned short l = f2bf(v - bf2f(h));
    const int hiSize = nOt[m] * 2048;
    dst[dOff[m] + i] = h;
    dst[dOff[m] + hiSize + i] = l;
}

// ---------------------------------------------------------------------------
// conv_offm: 27-ch 3x3 conv per pixel + softmax(mask) -> offm[py9|px9|mask9]
// 2 waves/block, 4 pixels/wave; lanes split channels (c=lane, c=lane+64).
// ---------------------------------------------------------------------------
__global__ __launch_bounds__(128, 1) void conv_offm(
    const float* __restrict__ x, const float* __restrict__ wcomb,
    const float* __restrict__ bcomb, float* __restrict__ offm)
{
    const int lane = threadIdx.x & 63;
    const int wid  = threadIdx.x >> 6;
    const int gp0  = (blockIdx.x * 2 + wid) * 4;     // 4 consecutive pixels, same row
    const int h0   = gp0 >> 7;
    const int w0   = gp0 & 127;

    float acc[4][27];
    #pragma unroll
    for (int p = 0; p < 4; ++p)
        #pragma unroll
        for (int o = 0; o < 27; ++o) acc[p][o] = 0.f;

    for (int k = 0; k < 9; ++k) {
        const int dy = k / 3 - 1, dx = k % 3 - 1;
        const int ny = h0 + dy;
        float xv0[4], xv1[4];
        #pragma unroll
        for (int p = 0; p < 4; ++p) {
            const int nx = w0 + p + dx;
            const bool ok = (ny >= 0) & (ny < HH) & (nx >= 0) & (nx < WW);
            const float* xb = x + (((ny < 0 ? 0 : (ny > 127 ? 127 : ny)) << 7)
                                   + (nx < 0 ? 0 : (nx > 127 ? 127 : nx))) * 128;
            xv0[p] = ok ? xb[lane]      : 0.f;
            xv1[p] = ok ? xb[lane + 64] : 0.f;
        }
        const float* wb = wcomb + k * 27 * 128;
        #pragma unroll
        for (int o = 0; o < 27; ++o) {
            const float wv0 = wb[o * 128 + lane];
            const float wv1 = wb[o * 128 + 64 + lane];
            #pragma unroll
            for (int p = 0; p < 4; ++p)
                acc[p][o] = fmaf(xv0[p], wv0, fmaf(xv1[p], wv1, acc[p][o]));
        }
    }

    // cross-lane butterfly reduce each of the 108 partials
    #pragma unroll
    for (int p = 0; p < 4; ++p)
        #pragma unroll
        for (int o = 0; o < 27; ++o) {
            float v = acc[p][o];
            v += __shfl_xor(v, 32);
            v += __shfl_xor(v, 16);
            v += __shfl_xor(v, 8);
            v += __shfl_xor(v, 4);
            v += __shfl_xor(v, 2);
            v += __shfl_xor(v, 1);
            acc[p][o] = v;
        }

    #pragma unroll
    for (int p = 0; p < 4; ++p) {
        if (lane == p) {
            const int gp = gp0 + p;
            const int hh = gp >> 7, ww = gp & 127;
            float vals[27];
            #pragma unroll
            for (int o = 0; o < 27; ++o) vals[o] = acc[p][o] + bcomb[o];
            float mx = vals[18];
            #pragma unroll
            for (int k = 1; k < 9; ++k) mx = fmaxf(mx, vals[18 + k]);
            float e[9], se = 0.f;
            #pragma unroll
            for (int k = 0; k < 9; ++k) { e[k] = expf(vals[18 + k] - mx); se += e[k]; }
            const float inv = 1.f / se;
            float* ob = offm + gp * 27;
            #pragma unroll
            for (int k = 0; k < 9; ++k) {
                ob[k]      = (float)(hh - 1 + k / 3) + vals[2 * k];      // py
                ob[9 + k]  = (float)(ww - 1 + k % 3) + vals[2 * k + 1];  // px
                ob[18 + k] = e[k] * inv;                                 // mask
            }
        }
    }
}

// ---------------------------------------------------------------------------
// deform: bilinear gather -> bf16 LDS, then MFMA 16x16x32 bf16 GEMM.
// 16 px/block, 4 waves. LDS rows padded to 1160 bf16.
// ---------------------------------------------------------------------------
__global__ __launch_bounds__(256, 1) void deform_kernel(
    const float* __restrict__ x, const float* __restrict__ offm,
    const unsigned short* __restrict__ wBu, const float* __restrict__ cb,
    float* __restrict__ y)
{
    __shared__ unsigned short smp[16 * 1160];   // 37120 B -> 4 blocks/CU

    const int lane = threadIdx.x & 63;
    const int wid  = threadIdx.x >> 6;          // 0..3
    const int gp0  = blockIdx.x * 16;

    // ---- phase 1: wave wid gathers pixels [4*wid, 4*wid+4) ----
    for (int pp = 0; pp < 4; ++pp) {
        const int pl = wid * 4 + pp;            // 0..15
        const float* ob = offm + (gp0 + pl) * 27;
        unsigned* dst = (unsigned*)smp + pl * 580 + lane;
        for (int k = 0; k < 9; ++k) {
            const float py = ob[k], px = ob[9 + k], mk = ob[18 + k];
            const float y0f = floorf(py), x0f = floorf(px);
            const int iy0 = (int)y0f, ix0 = (int)x0f;
            const float wy1 = py - y0f, wy0 = 1.f - wy1;
            const float wx1 = px - x0f, wx0 = 1.f - wx1;
            float s0 = 0.f, s1 = 0.f;
            #pragma unroll
            for (int cy = 0; cy < 2; ++cy) {
                const int yy = iy0 + cy;
                if (yy < 0 || yy > 127) continue;
                const float wy = cy ? wy1 : wy0;
                #pragma unroll
                for (int cx = 0; cx < 2; ++cx) {
                    const int xx = ix0 + cx;
                    if (xx < 0 || xx > 127) continue;
                    const float wgt = wy * (cx ? wx1 : wx0);
                    const float2 v = ((const float2*)(x + (((yy << 7) + xx) << 7)))[lane];
                    s0 = fmaf(wgt, v.x, s0);
                    s1 = fmaf(wgt, v.y, s1);
                }
            }
            s0 *= mk; s1 *= mk;
            dst[k * 64] = (unsigned)f2bf(s0) | ((unsigned)f2bf(s1) << 16);
        }
    }
    __syncthreads();

    // ---- phase 2: MFMA. wave wid handles out-tiles t = 2*wid, 2*wid+1 ----
    floatx4 acc0 = {0.f, 0.f, 0.f, 0.f};
    floatx4 acc1 = {0.f, 0.f, 0.f, 0.f};
    const int mrow = lane & 15;
    const int quad = lane >> 4;
    const unsigned short* arow = smp + mrow * 1160 + quad * 8;
    const int t0 = wid * 2, t1 = wid * 2 + 1;
    #pragma unroll 4
    for (int s = 0; s < 36; ++s) {
        const bf16x8 a  = *(const bf16x8*)(arow + s * 32);
        const bf16x8 b0 = *(const bf16x8*)(wBu + (((s * 8 + t0) * 64 + lane) << 3));
        const bf16x8 b1 = *(const bf16x8*)(wBu + (((s * 8 + t1) * 64 + lane) << 3));
        acc0 = __builtin_amdgcn_mfma_f32_16x16x32_bf16(a, b0, acc0, 0, 0, 0);
        acc1 = __builtin_amdgcn_mfma_f32_16x16x32_bf16(a, b1, acc1, 0, 0, 0);
    }

    // ---- epilogue: D col=lane&15, row=quad*4+reg; add conv bias ----
    const int n0 = t0 * 16 + mrow, n1 = t1 * 16 + mrow;
    const float bias0 = cb[n0], bias1 = cb[n1];
    #pragma unroll
    for (int r = 0; r < 4; ++r) {
        float* yr = y + (size_t)(gp0 + quad * 4 + r) * 128;
        yr[n0] = acc0[r] + bias0;
        yr[n1] = acc1[r] + bias1;
    }
}

// ---------------------------------------------------------------------------
// Per-channel sum / sumsq over the image (for the BN-style normalization).
// ---------------------------------------------------------------------------
__global__ __launch_bounds__(256) void stats_kernel(
    const float* __restrict__ y, float* __restrict__ stats)
{
    const int g = blockIdx.x * 256 + threadIdx.x;   // grid 256 -> 65536 threads
    float s = 0.f, q = 0.f;
    for (int i = g; i < NELEM; i += 65536) {
        const float v = y[i];
        s += v;
        q = fmaf(v, v, q);
    }
    __shared__ float ls[256], lq[256];
    ls[threadIdx.x] = s; lq[threadIdx.x] = q;
    __syncthreads();
    if (threadIdx.x < 128) {
        atomicAdd(&stats[threadIdx.x],       ls[threadIdx.x] + ls[threadIdx.x + 128]);
        atomicAdd(&stats[128 + threadIdx.x], lq[threadIdx.x] + lq[threadIdx.x + 128]);
    }
}

__global__ __launch_bounds__(256) void norm_relu(
    float* __restrict__ y, const float* __restrict__ stats,
    const float* __restrict__ bg, const float* __restrict__ bb)
{
    const int g = blockIdx.x * 256 + threadIdx.x;
    const int c = g & 127;
    const float mean = stats[c] * (1.f / 16384.f);
    const float var  = stats[128 + c] * (1.f / 16384.f) - mean * mean;
    const float rstd = rsqrtf(var + EPS);
    const float scale = bg[c] * rstd;
    const float shift = bb[c] - mean * scale;
    for (int i = g; i < NELEM; i += 65536)
        y[i] = fmaxf(fmaf(y[i], scale, shift), 0.f);
}

// ---------------------------------------------------------------------------
// 1x1 projection as hi/lo-split bf16 MFMA GEMM (fp32-accurate).
// Grid 256 blocks x 4 waves; block = 64 px. Stage x as hi/lo bf16 rows in
// LDS (stride 136 ushort -> 2-way banks = free). A = weights (m=o) from
// pre-swizzled frag planes, held in regs per o-tile; B = x from LDS
// (n=pixel). 3 MFMAs per K-step: xh*wh + xl*wh + xh*wl. D col=pixel ->
// coalesced NCHW writes.
// ---------------------------------------------------------------------------
__global__ __launch_bounds__(256) void proj_kernel(
    const float* __restrict__ xin, const unsigned short* __restrict__ aP,
    float* __restrict__ out, int O, int hiSize, int accum)
{
    __shared__ unsigned short sh[64 * 136];
    __shared__ unsigned short sl[64 * 136];
    const int gp0 = blockIdx.x * 64;

    // stage 64 px x 128 c, split into hi/lo bf16 (dword-packed writes)
    for (int i = threadIdx.x; i < 4096; i += 256) {
        const int p = i >> 6, c2 = (i & 63) * 2;
        const float2 v = *(const float2*)(xin + (gp0 + p) * 128 + c2);
        const unsigned short h0 = f2bf(v.x), h1 = f2bf(v.y);
        const unsigned short l0 = f2bf(v.x - bf2f(h0)), l1 = f2bf(v.y - bf2f(h1));
        ((unsigned*)sh)[p * 68 + (c2 >> 1)] = (unsigned)h0 | ((unsigned)h1 << 16);
        ((unsigned*)sl)[p * 68 + (c2 >> 1)] = (unsigned)l0 | ((unsigned)l1 << 16);
    }
    __syncthreads();

    const int lane = threadIdx.x & 63;
    const int wid  = threadIdx.x >> 6;
    const int quad = lane >> 4;
    const int nrow = lane & 15;
    const int nOt  = (O + 15) >> 4;

    for (int ot = wid; ot < nOt; ot += 4) {
        // A fragments for this o-tile (hi & lo), all 4 K-steps, in registers
        bf16x8 Ah[4], Al[4];
        #pragma unroll
        for (int s = 0; s < 4; ++s) {
            const int idx = ((ot * 4 + s) * 64 + lane) * 8;
            Ah[s] = *(const bf16x8*)(aP + idx);
            Al[s] = *(const bf16x8*)(aP + hiSize + idx);
        }
        #pragma unroll
        for (int pt = 0; pt < 4; ++pt) {
            floatx4 acc = {0.f, 0.f, 0.f, 0.f};
            const int roff = (pt * 16 + nrow) * 136 + quad * 8;
            #pragma unroll
            for (int s = 0; s < 4; ++s) {
                const bf16x8 Bh = *(const bf16x8*)(sh + roff + s * 32);
                const bf16x8 Bl = *(const bf16x8*)(sl + roff + s * 32);
                acc = __builtin_amdgcn_mfma_f32_16x16x32_bf16(Ah[s], Bh, acc, 0, 0, 0);
                acc = __builtin_amdgcn_mfma_f32_16x16x32_bf16(Al[s], Bh, acc, 0, 0, 0);
                acc = __builtin_amdgcn_mfma_f32_16x16x32_bf16(Ah[s], Bl, acc, 0, 0, 0);
            }
            #pragma unroll
            for (int r = 0; r < 4; ++r) {
                const int o = ot * 16 + quad * 4 + r;
                if (o < O) {
                    float* dst = out + (size_t)o * NPIX + gp0 + pt * 16 + nrow;
                    *dst = accum ? (*dst + acc[r]) : acc[r];
                }
            }
        }
    }
}

// ---------------------------------------------------------------------------
// Final layernorm over the W axis: one wave per (c,h) row of 128.
// ---------------------------------------------------------------------------
__global__ __launch_bounds__(256) void final_ln(
    float* __restrict__ out, const float* __restrict__ lnw,
    const float* __restrict__ lnb)
{
    const int lane = threadIdx.x & 63;
    const int wid  = threadIdx.x >> 6;
    const int row  = blockIdx.x * 4 + wid;          // 98304 rows
    float* rp = out + row * 128;
    const float v0 = rp[lane], v1 = rp[lane + 64];
    float s = v0 + v1;
    float q = v0 * v0 + v1 * v1;
    #pragma unroll
    for (int m = 32; m; m >>= 1) {
        s += __shfl_xor(s, m);
        q += __shfl_xor(q, m);
    }
    const float mean = s * (1.f / 128.f);
    const float var  = q * (1.f / 128.f) - mean * mean;
    const float rstd = rsqrtf(var + EPS);
    rp[lane]      = (v0 - mean) * rstd * lnw[lane]      + lnb[lane];
    rp[lane + 64] = (v1 - mean) * rstd * lnw[lane + 64] + lnb[lane + 64];
}

// ---------------------------------------------------------------------------
extern "C" void kernel_launch(void* const* d_in, const int* in_sizes, int n_in,
                              void* d_out, int out_size, void* d_ws, size_t ws_size,
                              hipStream_t stream)
{
    const float* xin[5];
    for (int i = 0; i < 5; ++i) xin[i] = (const float*)d_in[i];
    const float* b_cw[2] = {(const float*)d_in[5],  (const float*)d_in[11]};
    const float* b_cb[2] = {(const float*)d_in[6],  (const float*)d_in[12]};
    const float* b_ow[2] = {(const float*)d_in[7],  (const float*)d_in[13]};
    const float* b_mw[2] = {(const float*)d_in[8],  (const float*)d_in[14]};
    const float* b_bg[2] = {(const float*)d_in[9],  (const float*)d_in[15]};
    const float* b_bb[2] = {(const float*)d_in[10], (const float*)d_in[16]};
    const float* pw[8];
    for (int i = 0; i < 8; ++i) pw[i] = (const float*)d_in[17 + i];
    const float* lnw = (const float*)d_in[25];
    const float* lnb = (const float*)d_in[26];

    float* W = (float*)d_ws;
    float* out = (float*)d_out;
    unsigned short* wB = (unsigned short*)(W + OFF_WB);
    unsigned short* aP = (unsigned short*)(W + OFF_APROJ);

    hipMemsetAsync(W + OFF_STATS, 0, 2560 * sizeof(float), stream);

    setup_conv<<<704, 256, 0, stream>>>(b_cw[0], b_cb[0], b_ow[0], b_mw[0],
        W + OFF_WCOMB, W + OFF_BCOMB, wB);
    setup_conv<<<704, 256, 0, stream>>>(b_cw[1], b_cb[1], b_ow[1], b_mw[1],
        W + OFF_WCOMB + 31104, W + OFF_BCOMB + 32, wB + 147456);
    setup_projA<<<760, 256, 0, stream>>>(pw[0], pw[1], pw[2], pw[3],
        pw[4], pw[5], pw[6], pw[7], aP);

    static const int Obase[5] = {0, 20, 100, 250, 460};
    static const int Ocnt[5]  = {20, 80, 150, 210, 308};
    // A-frag plane offsets (ushort) and hi-plane sizes: m = c1,c2,c3a,c3b,c4a,c4b,c5a,c5b
    static const int aOffA[5] = {0, 8192, 28672, 110592, 225280};      // c1,c2,c3a,c4a,c5a
    static const int aOffB[5] = {0, 0, 69632, 167936, 307200};         // c3b,c4b,c5b
    static const int hiSz[5]  = {4096, 10240, 20480, 28672, 40960};

    for (int img = 0; img < 5; ++img) {
        for (int blk = 0; blk < 2; ++blk) {
            const float* xb = (blk == 0) ? xin[img] : (W + OFF_BUFA);
            float* yb = (blk == 0) ? (W + OFF_BUFA) : (W + OFF_BUFB);
            conv_offm<<<2048, 128, 0, stream>>>(
                xb, W + OFF_WCOMB + blk * 31104, W + OFF_BCOMB + blk * 32,
                W + OFF_OFFM);
            deform_kernel<<<1024, 256, 0, stream>>>(
                xb, W + OFF_OFFM, wB + blk * 147456, b_cb[blk], yb);
            float* st = W + OFF_STATS + (img * 2 + blk) * 256;
            stats_kernel<<<256, 256, 0, stream>>>(yb, st);
            norm_relu<<<256, 256, 0, stream>>>(yb, st, b_bg[blk], b_bb[blk]);
        }
        float* outb = out + (size_t)Obase[img] * NPIX;
        proj_kernel<<<256, 256, 0, stream>>>(
            W + OFF_BUFB, aP + aOffA[img], outb, Ocnt[img], hiSz[img], 0);
        if (img >= 2)
            proj_kernel<<<256, 256, 0, stream>>>(
                xin[img], aP + aOffB[img], outb, Ocnt[img], hiSz[img], 1);
    }
    final_ln<<<24576, 256, 0, stream>>>(out, lnw, lnb);
}

// Round 7
// 1053.146 us; speedup vs baseline: 4.6362x; 1.3963x over previous
//
#include <hip/hip_runtime.h>
#include <math.h>

// Problem constants
#define HH 128
#define WW 128
#define CC 128
#define KK 9
#define NPIX 16384           // H*W
#define NELEM 2097152        // NPIX*C
#define EPS 1e-5f

// Workspace layout (float offsets)
#define OFF_WCOMB 0          // [2][9][27][128] fp32      = 62208
#define OFF_BCOMB 62208      // [2][32] fp32              = 64
#define OFF_WB    62272      // fp16 B-frag deform w: 2*147456 ushort = 147456 floats
#define OFF_WC    209728     // fp16 B-frag conv w:   2*36864 ushort  = 36864 floats
#define OFF_APROJ 246592     // hi/lo bf16 A-frag proj w: 389120 ushort = 194560 floats
#define OFF_OFFM  441152     // [16384][27]               = 442368
#define OFF_BUFA  883520     // [16384][128]              = 2097152
#define OFF_BUFB  2980672    // [16384][128]              = 2097152
#define OFF_STATS 5077824    // [10][2][128]              = 2560
#define WS_FLOATS 5080384    // ~20.3 MB

typedef __bf16    bf16x8 __attribute__((ext_vector_type(8)));
typedef _Float16  f16x8  __attribute__((ext_vector_type(8)));
typedef float     floatx4 __attribute__((ext_vector_type(4)));

__device__ __forceinline__ unsigned short f2bf(float f) {
    unsigned u = __float_as_uint(f);
    return (unsigned short)((u + 0x7FFF + ((u >> 16) & 1)) >> 16);   // RNE
}
__device__ __forceinline__ float bf2f(unsigned short h) {
    return __uint_as_float(((unsigned)h) << 16);
}
__device__ __forceinline__ unsigned short f2h(float f) {
    _Float16 h = (_Float16)f;                                        // v_cvt_f16_f32 (RNE)
    return __builtin_bit_cast(unsigned short, h);
}

// ---------------------------------------------------------------------------
// Setup: compose [ow;mw] @ cw -> 27-ch conv weights (layout [k][o][c]),
// composed bias, and swizzle cw into fp16 MFMA B-fragment order (deform):
//   kc = s*32 + (lane>>4)*8 + j (kc = k*128+c), o = t*16 + (lane&15)
// ---------------------------------------------------------------------------
__global__ __launch_bounds__(256) void setup_conv(
    const float* __restrict__ cw, const float* __restrict__ cb,
    const float* __restrict__ ow, const float* __restrict__ mw,
    float* __restrict__ wcomb, float* __restrict__ bcomb,
    unsigned short* __restrict__ wBu)
{
    int tid = blockIdx.x * 256 + threadIdx.x;
    if (tid < 31104) {
        int c = tid & 127;
        int o = (tid >> 7) % 27;
        int k = tid / 3456;                  // k in [0,9)
        const float* sel = (o < 18) ? (ow + o * 128) : (mw + (o - 18) * 128);
        float v = 0.f;
        for (int cp = 0; cp < 128; ++cp)
            v = fmaf(sel[cp], cw[cp * 1152 + c * 9 + k], v);
        wcomb[tid] = v;                      // wcomb[k][o][c]
    } else if (tid < 31104 + 27) {
        int o = tid - 31104;
        const float* sel = (o < 18) ? (ow + o * 128) : (mw + (o - 18) * 128);
        float v = 0.f;
        for (int cp = 0; cp < 128; ++cp)
            v = fmaf(sel[cp], cb[cp], v);
        bcomb[o] = v;
    } else if (tid >= 32768 && tid < 32768 + 147456) {
        int i = tid - 32768;
        int j    = i & 7;
        int lane = (i >> 3) & 63;
        int t    = (i >> 9) & 7;
        int s    = i >> 12;                  // 0..35
        int kc   = s * 32 + ((lane >> 4) << 3) + j;
        int o    = t * 16 + (lane & 15);
        wBu[i] = f2h(cw[o * 1152 + (kc & 127) * 9 + (kc >> 7)]);
    }
}

// ---------------------------------------------------------------------------
// Swizzle composed conv weights wcomb[k][o][c] into fp16 B-frag order for the
// conv_offm MFMA (27 outputs padded to 32 -> 2 out-tiles):
//   i = ((s*2 + t)*64 + lane)*8 + j; kc = s*32 + (lane>>4)*8 + j;
//   o = t*16 + (lane&15). 36864 elements per conv block.
// ---------------------------------------------------------------------------
__global__ __launch_bounds__(256) void setup_convfrag(
    const float* __restrict__ wcomb, unsigned short* __restrict__ wC)
{
    int i = blockIdx.x * 256 + threadIdx.x;
    if (i >= 36864) return;
    int j    = i & 7;
    int lane = (i >> 3) & 63;
    int grp  = i >> 9;                       // s*2 + t
    int t = grp & 1, s = grp >> 1;
    int kc = s * 32 + ((lane >> 4) << 3) + j;
    int o  = t * 16 + (lane & 15);
    int c = kc & 127, k = kc >> 7;
    float v = (o < 27) ? wcomb[k * 3456 + o * 128 + c] : 0.f;
    wC[i] = f2h(v);
}

// ---------------------------------------------------------------------------
// Swizzle 8 projection matrices [O][128] into hi/lo bf16 A-fragment planes.
// ---------------------------------------------------------------------------
__global__ __launch_bounds__(256) void setup_projA(
    const float* __restrict__ s0, const float* __restrict__ s1,
    const float* __restrict__ s2, const float* __restrict__ s3,
    const float* __restrict__ s4, const float* __restrict__ s5,
    const float* __restrict__ s6, const float* __restrict__ s7,
    unsigned short* __restrict__ dst)
{
    const int Os[8]   = {20, 80, 150, 150, 210, 210, 308, 308};
    const int nOt[8]  = {2, 5, 10, 10, 14, 14, 20, 20};
    const int tOff[8] = {0, 4096, 14336, 34816, 55296, 83968, 112640, 153600};
    const int dOff[8] = {0, 8192, 28672, 69632, 110592, 167936, 225280, 307200};
    int tid = blockIdx.x * 256 + threadIdx.x;
    if (tid >= 194560) return;
    int m = 0;
    #pragma unroll
    for (int q = 1; q < 8; ++q) if (tid >= tOff[q]) m = q;
    const float* src;
    switch (m) {
        case 0: src = s0; break; case 1: src = s1; break;
        case 2: src = s2; break; case 3: src = s3; break;
        case 4: src = s4; break; case 5: src = s5; break;
        case 6: src = s6; break; default: src = s7; break;
    }
    int i = tid - tOff[m];
    int j    = i & 7;
    int lane = (i >> 3) & 63;
    int s    = (i >> 9) & 3;
    int ot   = i >> 11;
    int o = ot * 16 + (lane & 15);
    int c = s * 32 + ((lane >> 4) << 3) + j;
    float v = (o < Os[m]) ? src[o * 128 + c] : 0.f;
    unsigned short h = f2bf(v);
    unsigned short l = f2bf(v - bf2f(h));
    const int hiSize = nOt[m] * 2048;
    dst[dOff[m] + i] = h;
    dst[dOff[m] + hiSize + i] = l;
}

// ---------------------------------------------------------------------------
// conv_offm via fp16 MFMA. 16 px/block, 4 waves = (out-tile t, K-half kh).
// Gather: 9-tap clipped neighborhood -> fp16 LDS rows (deform layout,
// stride 1160 halves). 18 MFMAs/wave; cross-wave K-reduction through
// recycled LDS; 16-lane epilogue does softmax + offset assembly.
// ---------------------------------------------------------------------------
__global__ __launch_bounds__(256, 1) void conv_offm(
    const float* __restrict__ x, const unsigned short* __restrict__ wC,
    const float* __restrict__ bcomb, float* __restrict__ offm)
{
    __shared__ unsigned short smp[16 * 1160];   // 37120 B -> 4 blocks/CU
    float* red  = (float*)smp;                  // recycled: [2][16][16] = 512 f
    float* vals = red + 512;                    // recycled: [16][33]    = 528 f

    const int lane = threadIdx.x & 63;
    const int wid  = threadIdx.x >> 6;
    const int gp0  = blockIdx.x * 16;

    // ---- gather: wave wid handles pixels 4*wid..4*wid+3; lane = chan pair --
    for (int pp = 0; pp < 4; ++pp) {
        const int pl = wid * 4 + pp;
        const int gp = gp0 + pl;
        const int h0 = gp >> 7, w0 = gp & 127;
        unsigned* dst = (unsigned*)smp + pl * 580 + lane;
        #pragma unroll
        for (int k = 0; k < 9; ++k) {
            const int ny = h0 + k / 3 - 1;
            const int nx = w0 + k % 3 - 1;
            unsigned pack = 0;
            if (ny >= 0 && ny < 128 && nx >= 0 && nx < 128) {
                const float2 v = ((const float2*)(x + (((ny << 7) + nx) << 7)))[lane];
                pack = (unsigned)f2h(v.x) | ((unsigned)f2h(v.y) << 16);
            }
            dst[k * 64] = pack;
        }
    }
    __syncthreads();

    // ---- MFMA: wave = (t = wid&1, kh = wid>>1), 18 K-steps each ----
    const int t    = wid & 1;
    const int kh   = wid >> 1;
    const int mrow = lane & 15;
    const int quad = lane >> 4;
    floatx4 acc = {0.f, 0.f, 0.f, 0.f};
    const unsigned short* arow = smp + mrow * 1160 + quad * 8;
    #pragma unroll
    for (int j = 0; j < 18; ++j) {
        const int s = kh * 18 + j;
        const f16x8 a = *(const f16x8*)(arow + s * 32);
        const f16x8 b = *(const f16x8*)(wC + (((s * 2 + t) * 64 + lane) << 3));
        acc = __builtin_amdgcn_mfma_f32_16x16x32_f16(a, b, acc, 0, 0, 0);
    }
    __syncthreads();   // all smp reads done; safe to recycle as red/vals

    // D: row (pixel) = quad*4+r, col (channel n) = lane&15
    if (kh == 1) {
        #pragma unroll
        for (int r = 0; r < 4; ++r)
            red[t * 256 + (quad * 4 + r) * 16 + mrow] = acc[r];
    }
    __syncthreads();
    if (kh == 0) {
        #pragma unroll
        for (int r = 0; r < 4; ++r) {
            const float sv = acc[r] + red[t * 256 + (quad * 4 + r) * 16 + mrow];
            vals[(quad * 4 + r) * 33 + t * 16 + mrow] = sv;
        }
    }
    __syncthreads();

    // ---- epilogue: lane p < 16 handles pixel p ----
    if (threadIdx.x < 16) {
        const int p  = threadIdx.x;
        const int gp = gp0 + p;
        const int hh = gp >> 7, ww = gp & 127;
        float v[27];
        #pragma unroll
        for (int o = 0; o < 27; ++o) v[o] = vals[p * 33 + o] + bcomb[o];
        float mx = v[18];
        #pragma unroll
        for (int k = 1; k < 9; ++k) mx = fmaxf(mx, v[18 + k]);
        float e[9], se = 0.f;
        #pragma unroll
        for (int k = 0; k < 9; ++k) { e[k] = expf(v[18 + k] - mx); se += e[k]; }
        const float inv = 1.f / se;
        float* ob = offm + gp * 27;
        #pragma unroll
        for (int k = 0; k < 9; ++k) {
            ob[k]      = (float)(hh - 1 + k / 3) + v[2 * k];      // py
            ob[9 + k]  = (float)(ww - 1 + k % 3) + v[2 * k + 1];  // px
            ob[18 + k] = e[k] * inv;                              // mask
        }
    }
}

// ---------------------------------------------------------------------------
// deform: bilinear gather -> fp16 LDS, then MFMA 16x16x32 f16 GEMM.
// 16 px/block, 4 waves. LDS rows padded to 1160 halves.
// ---------------------------------------------------------------------------
__global__ __launch_bounds__(256, 1) void deform_kernel(
    const float* __restrict__ x, const float* __restrict__ offm,
    const unsigned short* __restrict__ wBu, const float* __restrict__ cb,
    float* __restrict__ y)
{
    __shared__ unsigned short smp[16 * 1160];   // 37120 B -> 4 blocks/CU

    const int lane = threadIdx.x & 63;
    const int wid  = threadIdx.x >> 6;          // 0..3
    const int gp0  = blockIdx.x * 16;

    // ---- phase 1: wave wid gathers pixels [4*wid, 4*wid+4) ----
    for (int pp = 0; pp < 4; ++pp) {
        const int pl = wid * 4 + pp;            // 0..15
        const float* ob = offm + (gp0 + pl) * 27;
        unsigned* dst = (unsigned*)smp + pl * 580 + lane;
        for (int k = 0; k < 9; ++k) {
            const float py = ob[k], px = ob[9 + k], mk = ob[18 + k];
            const float y0f = floorf(py), x0f = floorf(px);
            const int iy0 = (int)y0f, ix0 = (int)x0f;
            const float wy1 = py - y0f, wy0 = 1.f - wy1;
            const float wx1 = px - x0f, wx0 = 1.f - wx1;
            float s0 = 0.f, s1 = 0.f;
            #pragma unroll
            for (int cy = 0; cy < 2; ++cy) {
                const int yy = iy0 + cy;
                if (yy < 0 || yy > 127) continue;
                const float wy = cy ? wy1 : wy0;
                #pragma unroll
                for (int cx = 0; cx < 2; ++cx) {
                    const int xx = ix0 + cx;
                    if (xx < 0 || xx > 127) continue;
                    const float wgt = wy * (cx ? wx1 : wx0);
                    const float2 v = ((const float2*)(x + (((yy << 7) + xx) << 7)))[lane];
                    s0 = fmaf(wgt, v.x, s0);
                    s1 = fmaf(wgt, v.y, s1);
                }
            }
            s0 *= mk; s1 *= mk;
            dst[k * 64] = (unsigned)f2h(s0) | ((unsigned)f2h(s1) << 16);
        }
    }
    __syncthreads();

    // ---- phase 2: MFMA. wave wid handles out-tiles t = 2*wid, 2*wid+1 ----
    floatx4 acc0 = {0.f, 0.f, 0.f, 0.f};
    floatx4 acc1 = {0.f, 0.f, 0.f, 0.f};
    const int mrow = lane & 15;
    const int quad = lane >> 4;
    const unsigned short* arow = smp + mrow * 1160 + quad * 8;
    const int t0 = wid * 2, t1 = wid * 2 + 1;
    #pragma unroll 4
    for (int s = 0; s < 36; ++s) {
        const f16x8 a  = *(const f16x8*)(arow + s * 32);
        const f16x8 b0 = *(const f16x8*)(wBu + (((s * 8 + t0) * 64 + lane) << 3));
        const f16x8 b1 = *(const f16x8*)(wBu + (((s * 8 + t1) * 64 + lane) << 3));
        acc0 = __builtin_amdgcn_mfma_f32_16x16x32_f16(a, b0, acc0, 0, 0, 0);
        acc1 = __builtin_amdgcn_mfma_f32_16x16x32_f16(a, b1, acc1, 0, 0, 0);
    }

    // ---- epilogue: D col=lane&15, row=quad*4+reg; add conv bias ----
    const int n0 = t0 * 16 + mrow, n1 = t1 * 16 + mrow;
    const float bias0 = cb[n0], bias1 = cb[n1];
    #pragma unroll
    for (int r = 0; r < 4; ++r) {
        float* yr = y + (size_t)(gp0 + quad * 4 + r) * 128;
        yr[n0] = acc0[r] + bias0;
        yr[n1] = acc1[r] + bias1;
    }
}

// ---------------------------------------------------------------------------
// Per-channel sum / sumsq over the image (for the BN-style normalization).
// ---------------------------------------------------------------------------
__global__ __launch_bounds__(256) void stats_kernel(
    const float* __restrict__ y, float* __restrict__ stats)
{
    const int g = blockIdx.x * 256 + threadIdx.x;   // grid 256 -> 65536 threads
    float s = 0.f, q = 0.f;
    for (int i = g; i < NELEM; i += 65536) {
        const float v = y[i];
        s += v;
        q = fmaf(v, v, q);
    }
    __shared__ float ls[256], lq[256];
    ls[threadIdx.x] = s; lq[threadIdx.x] = q;
    __syncthreads();
    if (threadIdx.x < 128) {
        atomicAdd(&stats[threadIdx.x],       ls[threadIdx.x] + ls[threadIdx.x + 128]);
        atomicAdd(&stats[128 + threadIdx.x], lq[threadIdx.x] + lq[threadIdx.x + 128]);
    }
}

__global__ __launch_bounds__(256) void norm_relu(
    float* __restrict__ y, const float* __restrict__ stats,
    const float* __restrict__ bg, const float* __restrict__ bb)
{
    const int g = blockIdx.x * 256 + threadIdx.x;
    const int c = g & 127;
    const float mean = stats[c] * (1.f / 16384.f);
    const float var  = stats[128 + c] * (1.f / 16384.f) - mean * mean;
    const float rstd = rsqrtf(var + EPS);
    const float scale = bg[c] * rstd;
    const float shift = bb[c] - mean * scale;
    for (int i = g; i < NELEM; i += 65536)
        y[i] = fmaxf(fmaf(y[i], scale, shift), 0.f);
}

// ---------------------------------------------------------------------------
// 1x1 projection as hi/lo-split bf16 MFMA GEMM (fp32-accurate).
// ---------------------------------------------------------------------------
__global__ __launch_bounds__(256) void proj_kernel(
    const float* __restrict__ xin, const unsigned short* __restrict__ aP,
    float* __restrict__ out, int O, int hiSize, int accum)
{
    __shared__ unsigned short sh[64 * 136];
    __shared__ unsigned short sl[64 * 136];
    const int gp0 = blockIdx.x * 64;

    // stage 64 px x 128 c, split into hi/lo bf16 (dword-packed writes)
    for (int i = threadIdx.x; i < 4096; i += 256) {
        const int p = i >> 6, c2 = (i & 63) * 2;
        const float2 v = *(const float2*)(xin + (gp0 + p) * 128 + c2);
        const unsigned short h0 = f2bf(v.x), h1 = f2bf(v.y);
        const unsigned short l0 = f2bf(v.x - bf2f(h0)), l1 = f2bf(v.y - bf2f(h1));
        ((unsigned*)sh)[p * 68 + (c2 >> 1)] = (unsigned)h0 | ((unsigned)h1 << 16);
        ((unsigned*)sl)[p * 68 + (c2 >> 1)] = (unsigned)l0 | ((unsigned)l1 << 16);
    }
    __syncthreads();

    const int lane = threadIdx.x & 63;
    const int wid  = threadIdx.x >> 6;
    const int quad = lane >> 4;
    const int nrow = lane & 15;
    const int nOt  = (O + 15) >> 4;

    for (int ot = wid; ot < nOt; ot += 4) {
        bf16x8 Ah[4], Al[4];
        #pragma unroll
        for (int s = 0; s < 4; ++s) {
            const int idx = ((ot * 4 + s) * 64 + lane) * 8;
            Ah[s] = *(const bf16x8*)(aP + idx);
            Al[s] = *(const bf16x8*)(aP + hiSize + idx);
        }
        #pragma unroll
        for (int pt = 0; pt < 4; ++pt) {
            floatx4 acc = {0.f, 0.f, 0.f, 0.f};
            const int roff = (pt * 16 + nrow) * 136 + quad * 8;
            #pragma unroll
            for (int s = 0; s < 4; ++s) {
                const bf16x8 Bh = *(const bf16x8*)(sh + roff + s * 32);
                const bf16x8 Bl = *(const bf16x8*)(sl + roff + s * 32);
                acc = __builtin_amdgcn_mfma_f32_16x16x32_bf16(Ah[s], Bh, acc, 0, 0, 0);
                acc = __builtin_amdgcn_mfma_f32_16x16x32_bf16(Al[s], Bh, acc, 0, 0, 0);
                acc = __builtin_amdgcn_mfma_f32_16x16x32_bf16(Ah[s], Bl, acc, 0, 0, 0);
            }
            #pragma unroll
            for (int r = 0; r < 4; ++r) {
                const int o = ot * 16 + quad * 4 + r;
                if (o < O) {
                    float* dst = out + (size_t)o * NPIX + gp0 + pt * 16 + nrow;
                    *dst = accum ? (*dst + acc[r]) : acc[r];
                }
            }
        }
    }
}

// ---------------------------------------------------------------------------
// Final layernorm over the W axis: one wave per (c,h) row of 128.
// ---------------------------------------------------------------------------
__global__ __launch_bounds__(256) void final_ln(
    float* __restrict__ out, const float* __restrict__ lnw,
    const float* __restrict__ lnb)
{
    const int lane = threadIdx.x & 63;
    const int wid  = threadIdx.x >> 6;
    const int row  = blockIdx.x * 4 + wid;          // 98304 rows
    float* rp = out + row * 128;
    const float v0 = rp[lane], v1 = rp[lane + 64];
    float s = v0 + v1;
    float q = v0 * v0 + v1 * v1;
    #pragma unroll
    for (int m = 32; m; m >>= 1) {
        s += __shfl_xor(s, m);
        q += __shfl_xor(q, m);
    }
    const float mean = s * (1.f / 128.f);
    const float var  = q * (1.f / 128.f) - mean * mean;
    const float rstd = rsqrtf(var + EPS);
    rp[lane]      = (v0 - mean) * rstd * lnw[lane]      + lnb[lane];
    rp[lane + 64] = (v1 - mean) * rstd * lnw[lane + 64] + lnb[lane + 64];
}

// ---------------------------------------------------------------------------
extern "C" void kernel_launch(void* const* d_in, const int* in_sizes, int n_in,
                              void* d_out, int out_size, void* d_ws, size_t ws_size,
                              hipStream_t stream)
{
    const float* xin[5];
    for (int i = 0; i < 5; ++i) xin[i] = (const float*)d_in[i];
    const float* b_cw[2] = {(const float*)d_in[5],  (const float*)d_in[11]};
    const float* b_cb[2] = {(const float*)d_in[6],  (const float*)d_in[12]};
    const float* b_ow[2] = {(const float*)d_in[7],  (const float*)d_in[13]};
    const float* b_mw[2] = {(const float*)d_in[8],  (const float*)d_in[14]};
    const float* b_bg[2] = {(const float*)d_in[9],  (const float*)d_in[15]};
    const float* b_bb[2] = {(const float*)d_in[10], (const float*)d_in[16]};
    const float* pw[8];
    for (int i = 0; i < 8; ++i) pw[i] = (const float*)d_in[17 + i];
    const float* lnw = (const float*)d_in[25];
    const float* lnb = (const float*)d_in[26];

    float* W = (float*)d_ws;
    float* out = (float*)d_out;
    unsigned short* wB = (unsigned short*)(W + OFF_WB);
    unsigned short* wC = (unsigned short*)(W + OFF_WC);
    unsigned short* aP = (unsigned short*)(W + OFF_APROJ);

    hipMemsetAsync(W + OFF_STATS, 0, 2560 * sizeof(float), stream);

    setup_conv<<<704, 256, 0, stream>>>(b_cw[0], b_cb[0], b_ow[0], b_mw[0],
        W + OFF_WCOMB, W + OFF_BCOMB, wB);
    setup_conv<<<704, 256, 0, stream>>>(b_cw[1], b_cb[1], b_ow[1], b_mw[1],
        W + OFF_WCOMB + 31104, W + OFF_BCOMB + 32, wB + 147456);
    setup_convfrag<<<144, 256, 0, stream>>>(W + OFF_WCOMB, wC);
    setup_convfrag<<<144, 256, 0, stream>>>(W + OFF_WCOMB + 31104, wC + 36864);
    setup_projA<<<760, 256, 0, stream>>>(pw[0], pw[1], pw[2], pw[3],
        pw[4], pw[5], pw[6], pw[7], aP);

    static const int Obase[5] = {0, 20, 100, 250, 460};
    static const int Ocnt[5]  = {20, 80, 150, 210, 308};
    // A-frag plane offsets (ushort) and hi-plane sizes
    static const int aOffA[5] = {0, 8192, 28672, 110592, 225280};      // c1,c2,c3a,c4a,c5a
    static const int aOffB[5] = {0, 0, 69632, 167936, 307200};         // c3b,c4b,c5b
    static const int hiSz[5]  = {4096, 10240, 20480, 28672, 40960};

    for (int img = 0; img < 5; ++img) {
        for (int blk = 0; blk < 2; ++blk) {
            const float* xb = (blk == 0) ? xin[img] : (W + OFF_BUFA);
            float* yb = (blk == 0) ? (W + OFF_BUFA) : (W + OFF_BUFB);
            conv_offm<<<1024, 256, 0, stream>>>(
                xb, wC + blk * 36864, W + OFF_BCOMB + blk * 32, W + OFF_OFFM);
            deform_kernel<<<1024, 256, 0, stream>>>(
                xb, W + OFF_OFFM, wB + blk * 147456, b_cb[blk], yb);
            float* st = W + OFF_STATS + (img * 2 + blk) * 256;
            stats_kernel<<<256, 256, 0, stream>>>(yb, st);
            norm_relu<<<256, 256, 0, stream>>>(yb, st, b_bg[blk], b_bb[blk]);
        }
        float* outb = out + (size_t)Obase[img] * NPIX;
        proj_kernel<<<256, 256, 0, stream>>>(
            W + OFF_BUFB, aP + aOffA[img], outb, Ocnt[img], hiSz[img], 0);
        if (img >= 2)
            proj_kernel<<<256, 256, 0, stream>>>(
                xin[img], aP + aOffB[img], outb, Ocnt[img], hiSz[img], 1);
    }
    final_ln<<<24576, 256, 0, stream>>>(out, lnw, lnb);
}